// Round 1
// baseline (8412.592 us; speedup 1.0000x reference)
//
#include <hip/hip_runtime.h>
#include <cstddef>

// MusicVAE-style hierarchical decoder, fp32 correctness-first baseline.
// Structure:
//   conductor: 2-layer LSTM (CH=1024) over U=2 steps, constant input
//   codes c = ch @ co_W + co_b                        [U,B,512]
//   decoder: U=2 independent segments batched (rows = u*512+b), 16 steps,
//            2-layer LSTM (DH=1024), teacher-forced inputs precomputable
//   out = log_softmax(hs @ fc_W + fc_b), transposed to [B,SEQ,V]

namespace {

constexpr int kTile = 64;
constexpr int kBK = 16;

// Generic fused GEMM:
//   C[M,N] = act( (A1@B1) + (A2@B2) + Dmat + bias1 + bias2 )
// A1 rows < 512 come from A1a, rows >= 512 from A1b (if A1b != null);
// this implements the split "prev token" operand for the two decoder
// segments without materializing a concatenated input.
template <int ACT>  // 0 = none, 1 = tanh
__global__ __launch_bounds__(256) void gemm_kernel(
    const float* __restrict__ A1a, const float* __restrict__ A1b,
    int lda1, int K1,
    const float* __restrict__ B1, int ldb1,
    const float* __restrict__ A2, int lda2, int K2,
    const float* __restrict__ B2, int ldb2,
    const float* __restrict__ Dmat,
    const float* __restrict__ bias1, const float* __restrict__ bias2,
    float* __restrict__ C, int M, int N)
{
    __shared__ float As[kBK][kTile];
    __shared__ float Bs[kBK][kTile];

    const int tid = threadIdx.x;
    const int tx = tid & 15;
    const int ty = tid >> 4;
    const int bm = blockIdx.x * kTile;
    const int bn = blockIdx.y * kTile;

    float acc[4][4] = {};

    auto run_operand = [&](const float* Aa, const float* Ab, int lda, int K,
                           const float* Bm, int ldb) {
        const int ar = tid >> 2;         // 0..63: tile row for A loads
        const int akk = (tid & 3) * 4;   // 0,4,8,12: k offset within panel
        const int gr_a = bm + ar;
        const float* Arow = nullptr;
        if (gr_a < M) {
            Arow = (Ab != nullptr && gr_a >= 512)
                       ? (Ab + (size_t)(gr_a - 512) * lda)
                       : (Aa + (size_t)gr_a * lda);
        }
        const int bkr = tid >> 4;        // 0..15: k row for B loads
        const int bnc = (tid & 15) * 4;  // 0..60: col offset for B loads
        const bool a_vec_ok = ((lda & 3) == 0);
        const bool b_vec_ok = ((ldb & 3) == 0) && (bn + bnc + 3 < N);

        for (int k0 = 0; k0 < K; k0 += kBK) {
            // ---- load A panel (transposed into LDS) ----
            if (Arow != nullptr && a_vec_ok && (k0 + akk + 3 < K)) {
                const float4 v = *reinterpret_cast<const float4*>(Arow + k0 + akk);
                As[akk + 0][ar] = v.x;
                As[akk + 1][ar] = v.y;
                As[akk + 2][ar] = v.z;
                As[akk + 3][ar] = v.w;
            } else {
#pragma unroll
                for (int q = 0; q < 4; ++q) {
                    const int k = k0 + akk + q;
                    As[akk + q][ar] = (Arow != nullptr && k < K) ? Arow[k] : 0.f;
                }
            }
            // ---- load B panel ----
            {
                const int k = k0 + bkr;
                if (k < K && b_vec_ok) {
                    const float4 v = *reinterpret_cast<const float4*>(
                        Bm + (size_t)k * ldb + bn + bnc);
                    *reinterpret_cast<float4*>(&Bs[bkr][bnc]) = v;
                } else {
#pragma unroll
                    for (int q = 0; q < 4; ++q) {
                        const int n = bn + bnc + q;
                        Bs[bkr][bnc + q] = (k < K && n < N)
                                               ? Bm[(size_t)k * ldb + n]
                                               : 0.f;
                    }
                }
            }
            __syncthreads();
#pragma unroll
            for (int k = 0; k < kBK; ++k) {
                float a[4], b[4];
#pragma unroll
                for (int i = 0; i < 4; ++i) a[i] = As[k][ty * 4 + i];
#pragma unroll
                for (int j = 0; j < 4; ++j) b[j] = Bs[k][tx * 4 + j];
#pragma unroll
                for (int i = 0; i < 4; ++i)
#pragma unroll
                    for (int j = 0; j < 4; ++j)
                        acc[i][j] = fmaf(a[i], b[j], acc[i][j]);
            }
            __syncthreads();
        }
    };

    if (A1a != nullptr && K1 > 0) run_operand(A1a, A1b, lda1, K1, B1, ldb1);
    if (A2 != nullptr && K2 > 0) run_operand(A2, nullptr, lda2, K2, B2, ldb2);

#pragma unroll
    for (int i = 0; i < 4; ++i) {
        const int gr = bm + ty * 4 + i;
        if (gr >= M) continue;
#pragma unroll
        for (int j = 0; j < 4; ++j) {
            const int gc = bn + tx * 4 + j;
            if (gc >= N) continue;
            float v = acc[i][j];
            if (Dmat != nullptr) v += Dmat[(size_t)gr * N + gc];
            if (bias1 != nullptr) v += bias1[gc];
            if (bias2 != nullptr) v += bias2[gc];
            if (ACT == 1) v = tanhf(v);
            C[(size_t)gr * N + gc] = v;
        }
    }
}

// LSTM cell elementwise: gates G[r, 4*1024] (torch order i,f,g,o), H=1024.
// Updates c,h in place. Optionally also writes h to h_extra:
//   step_s >= 0: decoder mapping, row r = u*512+b -> hs[(u*16+step_s)*512+b]
//   step_s <  0: identity copy (conductor per-step output)
__global__ __launch_bounds__(256) void lstm_cell_kernel(
    const float* __restrict__ G, float* __restrict__ c, float* __restrict__ h,
    float* __restrict__ h_extra, int step_s, int total)
{
    const int idx = blockIdx.x * 256 + threadIdx.x;
    if (idx >= total) return;
    const int r = idx >> 10;
    const int j = idx & 1023;
    const float* g = G + ((size_t)r << 12);
    const float gi = g[j];
    const float gf = g[1024 + j];
    const float gg = g[2048 + j];
    const float go = g[3072 + j];
    const float si = 1.f / (1.f + expf(-gi));
    const float sf = 1.f / (1.f + expf(-gf));
    const float so = 1.f / (1.f + expf(-go));
    const float cn = fmaf(sf, c[idx], si * tanhf(gg));
    const float hn = so * tanhf(cn);
    c[idx] = cn;
    h[idx] = hn;
    if (h_extra != nullptr) {
        size_t dst;
        if (step_s >= 0) {
            const int u = r >> 9;
            const int b = r & 511;
            dst = (((size_t)((u * 16 + step_s) * 512 + b)) << 10) + j;
        } else {
            dst = (size_t)idx;
        }
        h_extra[dst] = hn;
    }
}

// SOS one-hot buffer: [512, 258], 1.0 at column 0.
__global__ void sos_init_kernel(float* __restrict__ sos)
{
    const int i = blockIdx.x * 256 + threadIdx.x;
    if (i < 512 * 258) sos[i] = ((i % 258) == 0) ? 1.f : 0.f;
}

// One block per row of logits [16384, 258]; row = t*512 + b.
// Writes out[b, t, v] = x - logsumexp(x).
__global__ __launch_bounds__(256) void logsoftmax_kernel(
    const float* __restrict__ logits, float* __restrict__ out)
{
    const int row = blockIdx.x;
    const int tid = threadIdx.x;
    const float* L = logits + (size_t)row * 258;
    const int t = row >> 9;
    const int b = row & 511;
    float* O = out + ((size_t)b * 32 + t) * 258;

    const float x0 = L[tid];
    const float x1 = (tid < 2) ? L[256 + tid] : -1e30f;

    __shared__ float sm[4];
    float m = fmaxf(x0, x1);
#pragma unroll
    for (int off = 32; off > 0; off >>= 1) m = fmaxf(m, __shfl_down(m, off));
    if ((tid & 63) == 0) sm[tid >> 6] = m;
    __syncthreads();
    m = fmaxf(fmaxf(sm[0], sm[1]), fmaxf(sm[2], sm[3]));
    __syncthreads();

    float s = expf(x0 - m) + ((tid < 2) ? expf(x1 - m) : 0.f);
#pragma unroll
    for (int off = 32; off > 0; off >>= 1) s += __shfl_down(s, off);
    if ((tid & 63) == 0) sm[tid >> 6] = s;
    __syncthreads();
    s = sm[0] + sm[1] + sm[2] + sm[3];

    const float lse = m + logf(s);
    O[tid] = x0 - lse;
    if (tid < 2) O[256 + tid] = x1 - lse;
}

}  // namespace

extern "C" void kernel_launch(void* const* d_in, const int* in_sizes, int n_in,
                              void* d_out, int out_size, void* d_ws, size_t ws_size,
                              hipStream_t stream)
{
    (void)in_sizes; (void)n_in; (void)out_size; (void)ws_size;

    const float* z    = (const float*)d_in[0];
    const float* x    = (const float*)d_in[1];   // [32,512,258]
    const float* cin  = (const float*)d_in[2];   // [1,512,258]
    const float* ciW  = (const float*)d_in[3];
    const float* cib  = (const float*)d_in[4];
    const float* cW1i = (const float*)d_in[5];
    const float* cW1h = (const float*)d_in[6];
    const float* cb1i = (const float*)d_in[7];
    const float* cb1h = (const float*)d_in[8];
    const float* cW2i = (const float*)d_in[9];
    const float* cW2h = (const float*)d_in[10];
    const float* cb2i = (const float*)d_in[11];
    const float* cb2h = (const float*)d_in[12];
    const float* coW  = (const float*)d_in[13];
    const float* cob  = (const float*)d_in[14];
    const float* diW  = (const float*)d_in[15];
    const float* dib  = (const float*)d_in[16];
    const float* dW1i = (const float*)d_in[17];  // [770,4096]
    const float* dW1h = (const float*)d_in[18];
    const float* db1i = (const float*)d_in[19];
    const float* db1h = (const float*)d_in[20];
    const float* dW2i = (const float*)d_in[21];
    const float* dW2h = (const float*)d_in[22];
    const float* db2i = (const float*)d_in[23];
    const float* db2h = (const float*)d_in[24];
    const float* fcW  = (const float*)d_in[25];  // [1024,258]
    const float* fcb  = (const float*)d_in[26];
    float* out = (float*)d_out;

    // ---- workspace layout (floats), ~158 MB total ----
    float* w = (float*)d_ws;
    size_t off = 0;
    auto alloc = [&](size_t n) { float* p = w + off; off += n; return p; };
    float* ch     = alloc((size_t)2 * 512 * 1024);   // conductor top hidden [U,B,CH]
    float* h1c    = alloc((size_t)512 * 1024);
    float* zc     = alloc((size_t)3 * 512 * 1024);   // c1c, h2c, c2c (zero-init)
    float* xW1c   = alloc((size_t)512 * 4096);       // conductor L1 input-gates
    float* Gbuf   = alloc((size_t)1024 * 4096);      // shared gate buffer
    float* ccode  = alloc((size_t)1024 * 512);       // codes, rows u*512+b
    float* cpre   = alloc((size_t)1024 * 4096);      // c @ dW1i[:512] + biases
    float* h1d    = alloc((size_t)1024 * 1024);
    float* zd     = alloc((size_t)3 * 1024 * 1024);  // c1d, h2d, c2d (zero-init)
    float* hs     = alloc((size_t)32 * 512 * 1024);  // top hidden, time-major
    float* logits = alloc((size_t)16384 * 258);
    float* sos    = alloc((size_t)512 * 258);

    float* c1c = zc;
    float* h2c = zc + (size_t)512 * 1024;
    float* c2c = zc + (size_t)2 * 512 * 1024;
    float* c1d = zd;
    float* h2d = zd + (size_t)1024 * 1024;
    float* c2d = zd + (size_t)2 * 1024 * 1024;

    hipMemsetAsync(zc, 0, (size_t)3 * 512 * 1024 * sizeof(float), stream);
    hipMemsetAsync(zd, 0, (size_t)3 * 1024 * 1024 * sizeof(float), stream);
    sos_init_kernel<<<dim3((512 * 258 + 255) / 256), 256, 0, stream>>>(sos);

    auto gemm = [&](int act,
                    const float* A1a, const float* A1b, int lda1, int K1,
                    const float* B1, int ldb1,
                    const float* A2, int lda2, int K2,
                    const float* B2, int ldb2,
                    const float* Dm, const float* b1, const float* b2,
                    float* C, int M, int N) {
        dim3 grid((M + kTile - 1) / kTile, (N + kTile - 1) / kTile);
        if (act == 1)
            gemm_kernel<1><<<grid, 256, 0, stream>>>(A1a, A1b, lda1, K1, B1, ldb1,
                                                     A2, lda2, K2, B2, ldb2,
                                                     Dm, b1, b2, C, M, N);
        else
            gemm_kernel<0><<<grid, 256, 0, stream>>>(A1a, A1b, lda1, K1, B1, ldb1,
                                                     A2, lda2, K2, B2, ldb2,
                                                     Dm, b1, b2, C, M, N);
    };
    auto cell = [&](const float* G, float* c, float* h, float* hx, int s, int M) {
        const int total = M * 1024;
        lstm_cell_kernel<<<dim3(total / 256), 256, 0, stream>>>(G, c, h, hx, s, total);
    };

    // ---- conductor ----
    // h1c = tanh(z @ ciW + cib)
    gemm(1, z, nullptr, 512, 512, ciW, 1024,
         nullptr, 0, 0, nullptr, 0, nullptr, cib, nullptr, h1c, 512, 1024);
    // xW1c = cin @ cW1i + cb1i + cb1h (constant input: compute once)
    gemm(0, cin, nullptr, 258, 258, cW1i, 4096,
         nullptr, 0, 0, nullptr, 0, nullptr, cb1i, cb1h, xW1c, 512, 4096);
    for (int u = 0; u < 2; ++u) {
        // G = xW1c + h1c @ cW1h
        gemm(0, h1c, nullptr, 1024, 1024, cW1h, 4096,
             nullptr, 0, 0, nullptr, 0, xW1c, nullptr, nullptr, Gbuf, 512, 4096);
        cell(Gbuf, c1c, h1c, nullptr, -1, 512);
        // G = h1c @ cW2i + h2c @ cW2h + cb2i + cb2h
        gemm(0, h1c, nullptr, 1024, 1024, cW2i, 4096,
             h2c, 1024, 1024, cW2h, 4096, nullptr, cb2i, cb2h, Gbuf, 512, 4096);
        cell(Gbuf, c2c, h2c, ch + (size_t)u * 512 * 1024, -1, 512);
    }

    // codes: ccode = ch @ coW + cob          [1024, 512]
    gemm(0, ch, nullptr, 1024, 1024, coW, 512,
         nullptr, 0, 0, nullptr, 0, nullptr, cob, nullptr, ccode, 1024, 512);
    // cpre = ccode @ dW1i[:512] + db1i + db1h (constant across the 16 steps)
    gemm(0, ccode, nullptr, 512, 512, dW1i, 4096,
         nullptr, 0, 0, nullptr, 0, nullptr, db1i, db1h, cpre, 1024, 4096);
    // h1d = tanh(ccode @ diW + dib)
    gemm(1, ccode, nullptr, 512, 512, diW, 1024,
         nullptr, 0, 0, nullptr, 0, nullptr, dib, nullptr, h1d, 1024, 1024);

    // ---- decoder: 16 steps, both segments batched (rows u*512+b) ----
    for (int s = 0; s < 16; ++s) {
        const float* plo = (s == 0) ? sos : (x + (size_t)(s - 1) * 512 * 258);
        const float* phi = x + (size_t)(15 + s) * 512 * 258;
        // G1 = cpre + prev @ dW1i[512:] + h1d @ dW1h
        gemm(0, plo, phi, 258, 258, dW1i + (size_t)512 * 4096, 4096,
             h1d, 1024, 1024, dW1h, 4096, cpre, nullptr, nullptr, Gbuf, 1024, 4096);
        cell(Gbuf, c1d, h1d, nullptr, -1, 1024);
        // G2 = h1d @ dW2i + h2d @ dW2h + db2i + db2h
        gemm(0, h1d, nullptr, 1024, 1024, dW2i, 4096,
             h2d, 1024, 1024, dW2h, 4096, nullptr, db2i, db2h, Gbuf, 1024, 4096);
        cell(Gbuf, c2d, h2d, hs, s, 1024);
    }

    // ---- projection + log_softmax (+ transpose to [B,SEQ,V]) ----
    gemm(0, hs, nullptr, 1024, 1024, fcW, 258,
         nullptr, 0, 0, nullptr, 0, nullptr, fcb, nullptr, logits, 16384, 258);
    logsoftmax_kernel<<<dim3(16384), 256, 0, stream>>>(logits, out);
}

// Round 2
// 1959.214 us; speedup vs baseline: 4.2939x; 4.2939x over previous
//
#include <hip/hip_runtime.h>
#include <cstddef>
#include <cstdint>

// MusicVAE-style hierarchical decoder — round 1: bf16 MFMA GEMMs.
//   - weights transposed+converted to bf16 [N][Kp] once per launch
//   - activations produced in bf16 by the LSTM cell kernel; c-states fp32
//   - GEMM: 64x128 tile, BK=32, 4 waves, global_load_lds staging, 2-phase dbuf

namespace {

typedef short s8v __attribute__((ext_vector_type(8)));
typedef float f4v __attribute__((ext_vector_type(4)));
typedef unsigned short ushort_t;

__device__ inline unsigned short f2bf(float f) {
    union { float f; unsigned u; } v; v.f = f;
    unsigned r = v.u + 0x7fff + ((v.u >> 16) & 1);
    return (unsigned short)(r >> 16);
}

#define GLOAD_LDS(gp, lp)                                              \
    __builtin_amdgcn_global_load_lds(                                  \
        (const __attribute__((address_space(1))) void*)(gp),           \
        (__attribute__((address_space(3))) void*)(lp), 16, 0, 0)

// C[M,N] = act( A1@B1t^T + A2@B2t^T + Dmat + bias1 + bias2 )
// A row-major bf16 [M][K]; Bt row-major bf16 [N][K] (pre-transposed weights).
// A1 rows >= 512 come from A1b when A1b != null (decoder prev-token split).
// K1, K2 multiples of 32. M multiple of 64. Output fp32 C and/or bf16 Cbf.
template <int ACT>
__global__ __launch_bounds__(256) void mfma_gemm(
    const ushort_t* __restrict__ A1a, const ushort_t* __restrict__ A1b,
    int lda1, int K1, const ushort_t* __restrict__ B1t,
    const ushort_t* __restrict__ A2, int lda2, int K2,
    const ushort_t* __restrict__ B2t,
    const float* __restrict__ Dmat, const float* __restrict__ bias1,
    const float* __restrict__ bias2,
    float* __restrict__ C, ushort_t* __restrict__ Cbf, int M, int N)
{
    __shared__ __align__(16) ushort_t lds[2][6144];  // [0:2048)=A 64x32, [2048:6144)=B 128x32

    const int tid = threadIdx.x;
    const int wid = tid >> 6;
    const int lane = tid & 63;
    const int bm = blockIdx.x * 64;
    const int bn = blockIdx.y * 128;
    const int n1 = K1 >> 5;
    const int n2 = K2 >> 5;
    const int nt = n1 + n2;

    // staging geometry: thread covers row (wid*16 + lane/4), k-chunk (lane%4)*8
    const int srow = wid * 16 + (lane >> 2);
    const int skc = (lane & 3) * 8;

    auto stage = [&](int buf, int t) {
        const ushort_t *Aa, *Ab, *Bt;
        int lda, ldb, k0;
        if (t < n1) {
            Aa = A1a; Ab = A1b; lda = lda1; Bt = B1t; ldb = K1; k0 = t * 32;
        } else {
            Aa = A2; Ab = nullptr; lda = lda2; Bt = B2t; ldb = K2; k0 = (t - n1) * 32;
        }
        const int grow = bm + srow;
        const ushort_t* ap = (Ab != nullptr && grow >= 512)
                                 ? (Ab + (size_t)(grow - 512) * lda + k0 + skc)
                                 : (Aa + (size_t)grow * lda + k0 + skc);
        GLOAD_LDS(ap, &lds[buf][wid * 512]);
        const ushort_t* bp0 = Bt + (size_t)(bn + srow) * ldb + k0 + skc;
        GLOAD_LDS(bp0, &lds[buf][2048 + wid * 512]);
        const ushort_t* bp1 = Bt + (size_t)(bn + 64 + srow) * ldb + k0 + skc;
        GLOAD_LDS(bp1, &lds[buf][4096 + wid * 512]);
    };

    const int wr = wid >> 1;      // 0..1 : 32-row block
    const int wc = wid & 1;       // 0..1 : 64-col block
    const int lrow = lane & 15;
    const int lkg = lane >> 4;    // 0..3

    f4v acc[2][4] = {};

    stage(0, 0);
    __syncthreads();
    int cur = 0;

    for (int t = 0; t < nt; ++t) {
        if (t + 1 < nt) stage(cur ^ 1, t + 1);

        const ushort_t* LA = &lds[cur][0];
        const ushort_t* LB = &lds[cur][2048];
        s8v af[2], bfr[4];
#pragma unroll
        for (int m = 0; m < 2; ++m)
            af[m] = *(const s8v*)(LA + (wr * 32 + m * 16 + lrow) * 32 + lkg * 8);
#pragma unroll
        for (int n = 0; n < 4; ++n)
            bfr[n] = *(const s8v*)(LB + (wc * 64 + n * 16 + lrow) * 32 + lkg * 8);
#pragma unroll
        for (int m = 0; m < 2; ++m)
#pragma unroll
            for (int n = 0; n < 4; ++n)
                acc[m][n] = __builtin_amdgcn_mfma_f32_16x16x32_bf16(
                    af[m], bfr[n], acc[m][n], 0, 0, 0);

        __syncthreads();
        cur ^= 1;
    }

    // epilogue: C/D layout col=lane&15, row=(lane>>4)*4+r  [verified m89]
#pragma unroll
    for (int m = 0; m < 2; ++m) {
        const int row = bm + wr * 32 + m * 16 + lkg * 4;
#pragma unroll
        for (int n = 0; n < 4; ++n) {
            const int col = bn + wc * 64 + n * 16 + lrow;
            if (col >= N) continue;
#pragma unroll
            for (int r = 0; r < 4; ++r) {
                const size_t o = (size_t)(row + r) * N + col;
                float v = acc[m][n][r];
                if (Dmat != nullptr) v += Dmat[o];
                if (bias1 != nullptr) v += bias1[col];
                if (bias2 != nullptr) v += bias2[col];
                if (ACT == 1) v = tanhf(v);
                if (C != nullptr) C[o] = v;
                if (Cbf != nullptr) Cbf[o] = f2bf(v);
            }
        }
    }
}

// LSTM cell: G [M][4096] fp32 (gate order i,f,g,o), c fp32 [M][1024] in/out,
// h bf16 [M][1024] out. Optional extra bf16 dest hx:
//   step_s >= 0: decoder mapping row r=u*512+b -> hs[(u*16+step_s)*512+b]
//   step_s <  0: identity copy.
__global__ __launch_bounds__(256) void lstm_cell(
    const float* __restrict__ G, float* __restrict__ c,
    ushort_t* __restrict__ h, ushort_t* __restrict__ hx, int step_s, int M)
{
    const int idx = blockIdx.x * 256 + threadIdx.x;  // one thread = 4 elements
    const int total = M << 8;
    if (idx >= total) return;
    const int r = idx >> 8;
    const int q = idx & 255;
    const float* g = G + ((size_t)r << 12) + (q << 2);
    const float4 vi = *(const float4*)(g);
    const float4 vf = *(const float4*)(g + 1024);
    const float4 vg = *(const float4*)(g + 2048);
    const float4 vo = *(const float4*)(g + 3072);
    float4 vc = *(const float4*)(c + ((size_t)idx << 2));

    float gi[4] = {vi.x, vi.y, vi.z, vi.w};
    float gf[4] = {vf.x, vf.y, vf.z, vf.w};
    float gg[4] = {vg.x, vg.y, vg.z, vg.w};
    float go[4] = {vo.x, vo.y, vo.z, vo.w};
    float cv[4] = {vc.x, vc.y, vc.z, vc.w};
    float cn[4], hn[4];
#pragma unroll
    for (int e = 0; e < 4; ++e) {
        const float si = 1.f / (1.f + expf(-gi[e]));
        const float sf = 1.f / (1.f + expf(-gf[e]));
        const float so = 1.f / (1.f + expf(-go[e]));
        cn[e] = fmaf(sf, cv[e], si * tanhf(gg[e]));
        hn[e] = so * tanhf(cn[e]);
    }
    float4 oc = {cn[0], cn[1], cn[2], cn[3]};
    ushort4 oh = {f2bf(hn[0]), f2bf(hn[1]), f2bf(hn[2]), f2bf(hn[3])};
    *(float4*)(c + ((size_t)idx << 2)) = oc;
    *(ushort4*)(h + ((size_t)idx << 2)) = oh;
    if (hx != nullptr) {
        size_t dst;
        if (step_s >= 0) {
            const int u = r >> 9, b = r & 511;
            dst = ((size_t)((u * 16 + step_s) * 512 + b) << 10) + (q << 2);
        } else {
            dst = (size_t)idx << 2;
        }
        *(ushort4*)(hx + dst) = oh;
    }
}

// out[n][k] (bf16, dims [Np][Kp]) = in[k][n] (fp32, valid [K][N]); zero-pads.
__global__ __launch_bounds__(256) void transpose_to_bf16(
    const float* __restrict__ in, ushort_t* __restrict__ out,
    int K, int N, int Kp, int Np)
{
    __shared__ float tile[32][33];
    const int k0 = blockIdx.x * 32, n0 = blockIdx.y * 32;
    const int tx = threadIdx.x, ty = threadIdx.y;  // 32 x 8
#pragma unroll
    for (int q = 0; q < 4; ++q) {
        const int k = k0 + ty + 8 * q, n = n0 + tx;
        tile[ty + 8 * q][tx] = (k < K && n < N) ? in[(size_t)k * N + n] : 0.f;
    }
    __syncthreads();
#pragma unroll
    for (int q = 0; q < 4; ++q) {
        const int n = n0 + ty + 8 * q, k = k0 + tx;
        out[(size_t)n * Kp + k] = f2bf(tile[tx][ty + 8 * q]);
    }
}

// out[r][kp] bf16 = in[r][k] fp32, zero-padded to Kp.
__global__ void convert_pad_bf16(const float* __restrict__ in,
                                 ushort_t* __restrict__ out,
                                 int K, int Kp, int total)
{
    const int idx = blockIdx.x * 256 + threadIdx.x;
    if (idx >= total) return;
    const int r = idx / Kp, k = idx - r * Kp;
    out[idx] = (k < K) ? f2bf(in[(size_t)r * K + k]) : (ushort_t)0;
}

// bf16 one-hot [512][288] with 1.0 at column 0.
__global__ void sos_init_bf16(ushort_t* __restrict__ sos)
{
    const int i = blockIdx.x * 256 + threadIdx.x;
    if (i < 512 * 288) sos[i] = ((i % 288) == 0) ? (ushort_t)0x3F80 : (ushort_t)0;
}

// One block per row of logits [16384, 258]; row = t*512 + b.
__global__ __launch_bounds__(256) void logsoftmax_kernel(
    const float* __restrict__ logits, float* __restrict__ out)
{
    const int row = blockIdx.x;
    const int tid = threadIdx.x;
    const float* L = logits + (size_t)row * 258;
    const int t = row >> 9;
    const int b = row & 511;
    float* O = out + ((size_t)b * 32 + t) * 258;

    const float x0 = L[tid];
    const float x1 = (tid < 2) ? L[256 + tid] : -1e30f;

    __shared__ float sm[4];
    float m = fmaxf(x0, x1);
#pragma unroll
    for (int off = 32; off > 0; off >>= 1) m = fmaxf(m, __shfl_down(m, off));
    if ((tid & 63) == 0) sm[tid >> 6] = m;
    __syncthreads();
    m = fmaxf(fmaxf(sm[0], sm[1]), fmaxf(sm[2], sm[3]));
    __syncthreads();

    float s = expf(x0 - m) + ((tid < 2) ? expf(x1 - m) : 0.f);
#pragma unroll
    for (int off = 32; off > 0; off >>= 1) s += __shfl_down(s, off);
    if ((tid & 63) == 0) sm[tid >> 6] = s;
    __syncthreads();
    s = sm[0] + sm[1] + sm[2] + sm[3];

    const float lse = m + logf(s);
    O[tid] = x0 - lse;
    if (tid < 2) O[256 + tid] = x1 - lse;
}

}  // namespace

extern "C" void kernel_launch(void* const* d_in, const int* in_sizes, int n_in,
                              void* d_out, int out_size, void* d_ws, size_t ws_size,
                              hipStream_t stream)
{
    (void)in_sizes; (void)n_in; (void)out_size; (void)ws_size;

    const float* z    = (const float*)d_in[0];
    const float* x    = (const float*)d_in[1];   // [32,512,258]
    const float* cin  = (const float*)d_in[2];   // [1,512,258]
    const float* ciW  = (const float*)d_in[3];
    const float* cib  = (const float*)d_in[4];
    const float* cW1i = (const float*)d_in[5];
    const float* cW1h = (const float*)d_in[6];
    const float* cb1i = (const float*)d_in[7];
    const float* cb1h = (const float*)d_in[8];
    const float* cW2i = (const float*)d_in[9];
    const float* cW2h = (const float*)d_in[10];
    const float* cb2i = (const float*)d_in[11];
    const float* cb2h = (const float*)d_in[12];
    const float* coW  = (const float*)d_in[13];
    const float* cob  = (const float*)d_in[14];
    const float* diW  = (const float*)d_in[15];
    const float* dib  = (const float*)d_in[16];
    const float* dW1i = (const float*)d_in[17];  // [770,4096]
    const float* dW1h = (const float*)d_in[18];
    const float* db1i = (const float*)d_in[19];
    const float* db1h = (const float*)d_in[20];
    const float* dW2i = (const float*)d_in[21];
    const float* dW2h = (const float*)d_in[22];
    const float* db2i = (const float*)d_in[23];
    const float* db2h = (const float*)d_in[24];
    const float* fcW  = (const float*)d_in[25];  // [1024,258]
    const float* fcb  = (const float*)d_in[26];
    float* out = (float*)d_out;

    // ---- workspace layout ----
    char* wsp = (char*)d_ws;
    size_t off = 0;
    auto allocf = [&](size_t n) { float* p = (float*)(wsp + off); off += n * 4; return p; };
    auto allocb = [&](size_t n) { ushort_t* p = (ushort_t*)(wsp + off); off += n * 2; return p; };

    // fp32
    float* xW1c   = allocf((size_t)512 * 4096);
    float* Gbuf   = allocf((size_t)1024 * 4096);
    float* cpre   = allocf((size_t)1024 * 4096);
    float* cst    = allocf((size_t)3 * 1024 * 1024);  // c1c,c2c,c1d,c2d
    float* logits = allocf((size_t)16384 * 258);
    float* c1c = cst;
    float* c2c = cst + (size_t)512 * 1024;
    float* c1d = cst + (size_t)1024 * 1024;
    float* c2d = cst + (size_t)2 * 1024 * 1024;

    // bf16 activations/inputs
    ushort_t* zbf   = allocb((size_t)512 * 512);
    ushort_t* cinbf = allocb((size_t)512 * 288);
    ushort_t* sosbf = allocb((size_t)512 * 288);
    ushort_t* xbf   = allocb((size_t)16384 * 288);
    ushort_t* h1c   = allocb((size_t)512 * 1024);
    ushort_t* h2c   = allocb((size_t)512 * 1024);
    ushort_t* chbf  = allocb((size_t)1024 * 1024);
    ushort_t* ccode = allocb((size_t)1024 * 512);
    ushort_t* h1d   = allocb((size_t)1024 * 1024);
    ushort_t* h2d   = allocb((size_t)1024 * 1024);
    ushort_t* hsbf  = allocb((size_t)16384 * 1024);
    // bf16 transposed weights [N][Kp]
    ushort_t* ciWt  = allocb((size_t)1024 * 512);
    ushort_t* cW1it = allocb((size_t)4096 * 288);
    ushort_t* cW1ht = allocb((size_t)4096 * 1024);
    ushort_t* cW2it = allocb((size_t)4096 * 1024);
    ushort_t* cW2ht = allocb((size_t)4096 * 1024);
    ushort_t* coWt  = allocb((size_t)512 * 1024);
    ushort_t* dtopt = allocb((size_t)4096 * 512);   // dW1i[:512]^T
    ushort_t* dbott = allocb((size_t)4096 * 288);   // dW1i[512:]^T (K padded)
    ushort_t* diWt  = allocb((size_t)1024 * 512);
    ushort_t* dW1ht = allocb((size_t)4096 * 1024);
    ushort_t* dW2it = allocb((size_t)4096 * 1024);
    ushort_t* dW2ht = allocb((size_t)4096 * 1024);
    ushort_t* fcWt  = allocb((size_t)384 * 1024);   // rows >= 258 zero

    // ---- zero-init states ----
    hipMemsetAsync(cst, 0, (size_t)3 * 1024 * 1024 * 4, stream);
    hipMemsetAsync(h2c, 0, (size_t)512 * 1024 * 2, stream);
    hipMemsetAsync(h2d, 0, (size_t)1024 * 1024 * 2, stream);

    // ---- weight transposes / input converts ----
    auto transp = [&](const float* in, ushort_t* o, int K, int N, int Kp, int Np) {
        transpose_to_bf16<<<dim3(Kp / 32, Np / 32), dim3(32, 8), 0, stream>>>(in, o, K, N, Kp, Np);
    };
    transp(ciW, ciWt, 512, 1024, 512, 1024);
    transp(cW1i, cW1it, 258, 4096, 288, 4096);
    transp(cW1h, cW1ht, 1024, 4096, 1024, 4096);
    transp(cW2i, cW2it, 1024, 4096, 1024, 4096);
    transp(cW2h, cW2ht, 1024, 4096, 1024, 4096);
    transp(coW, coWt, 1024, 512, 1024, 512);
    transp(dW1i, dtopt, 512, 4096, 512, 4096);
    transp(dW1i + (size_t)512 * 4096, dbott, 258, 4096, 288, 4096);
    transp(diW, diWt, 512, 1024, 512, 1024);
    transp(dW1h, dW1ht, 1024, 4096, 1024, 4096);
    transp(dW2i, dW2it, 1024, 4096, 1024, 4096);
    transp(dW2h, dW2ht, 1024, 4096, 1024, 4096);
    transp(fcW, fcWt, 1024, 258, 1024, 384);

    auto convert = [&](const float* in, ushort_t* o, int K, int Kp, int R) {
        const int total = R * Kp;
        convert_pad_bf16<<<dim3((total + 255) / 256), 256, 0, stream>>>(in, o, K, Kp, total);
    };
    convert(z, zbf, 512, 512, 512);
    convert(cin, cinbf, 258, 288, 512);
    convert(x, xbf, 258, 288, 16384);
    sos_init_bf16<<<dim3((512 * 288 + 255) / 256), 256, 0, stream>>>(sosbf);

    auto gemm = [&](int act,
                    const ushort_t* A1a, const ushort_t* A1b, int lda1, int K1,
                    const ushort_t* B1t,
                    const ushort_t* A2, int lda2, int K2, const ushort_t* B2t,
                    const float* Dm, const float* b1, const float* b2,
                    float* C, ushort_t* Cbf, int M, int N) {
        dim3 grid(M / 64, (N + 127) / 128);
        if (act)
            mfma_gemm<1><<<grid, 256, 0, stream>>>(A1a, A1b, lda1, K1, B1t,
                                                   A2, lda2, K2, B2t, Dm, b1, b2,
                                                   C, Cbf, M, N);
        else
            mfma_gemm<0><<<grid, 256, 0, stream>>>(A1a, A1b, lda1, K1, B1t,
                                                   A2, lda2, K2, B2t, Dm, b1, b2,
                                                   C, Cbf, M, N);
    };
    auto cell = [&](const float* G, float* c, ushort_t* h, ushort_t* hx, int s, int M) {
        lstm_cell<<<dim3(M), 256, 0, stream>>>(G, c, h, hx, s, M);
    };

    // ---- conductor ----
    gemm(1, zbf, nullptr, 512, 512, ciWt, nullptr, 0, 0, nullptr,
         nullptr, cib, nullptr, nullptr, h1c, 512, 1024);
    gemm(0, cinbf, nullptr, 288, 288, cW1it, nullptr, 0, 0, nullptr,
         nullptr, cb1i, cb1h, xW1c, nullptr, 512, 4096);
    for (int u = 0; u < 2; ++u) {
        gemm(0, h1c, nullptr, 1024, 1024, cW1ht, nullptr, 0, 0, nullptr,
             xW1c, nullptr, nullptr, Gbuf, nullptr, 512, 4096);
        cell(Gbuf, c1c, h1c, nullptr, -1, 512);
        gemm(0, h1c, nullptr, 1024, 1024, cW2it, h2c, 1024, 1024, cW2ht,
             nullptr, cb2i, cb2h, Gbuf, nullptr, 512, 4096);
        cell(Gbuf, c2c, h2c, chbf + (size_t)u * 512 * 1024, -1, 512);
    }

    // ---- codes + decoder init ----
    gemm(0, chbf, nullptr, 1024, 1024, coWt, nullptr, 0, 0, nullptr,
         nullptr, cob, nullptr, nullptr, ccode, 1024, 512);
    gemm(0, ccode, nullptr, 512, 512, dtopt, nullptr, 0, 0, nullptr,
         nullptr, db1i, db1h, cpre, nullptr, 1024, 4096);
    gemm(1, ccode, nullptr, 512, 512, diWt, nullptr, 0, 0, nullptr,
         nullptr, dib, nullptr, nullptr, h1d, 1024, 1024);

    // ---- decoder: 16 steps, both segments batched (rows u*512+b) ----
    for (int s = 0; s < 16; ++s) {
        const ushort_t* plo = (s == 0) ? sosbf : (xbf + (size_t)(s - 1) * 512 * 288);
        const ushort_t* phi = xbf + (size_t)(15 + s) * 512 * 288;
        gemm(0, plo, phi, 288, 288, dbott, h1d, 1024, 1024, dW1ht,
             cpre, nullptr, nullptr, Gbuf, nullptr, 1024, 4096);
        cell(Gbuf, c1d, h1d, nullptr, -1, 1024);
        gemm(0, h1d, nullptr, 1024, 1024, dW2it, h2d, 1024, 1024, dW2ht,
             nullptr, db2i, db2h, Gbuf, nullptr, 1024, 4096);
        cell(Gbuf, c2d, h2d, hsbf, s, 1024);
    }

    // ---- projection + log_softmax ----
    gemm(0, hsbf, nullptr, 1024, 1024, fcWt, nullptr, 0, 0, nullptr,
         nullptr, fcb, nullptr, logits, nullptr, 16384, 258);
    logsoftmax_kernel<<<dim3(16384), 256, 0, stream>>>(logits, out);
}

// Round 3
// 1365.417 us; speedup vs baseline: 6.1612x; 1.4349x over previous
//
#include <hip/hip_runtime.h>
#include <cstddef>
#include <cstdint>

// Round 2: fused LSTM-cell GEMM epilogue (gate-interleaved weights),
// layer-parallel step kernel (L2 step s || L1 step s+1), swizzled LDS.

namespace {

typedef short s8v __attribute__((ext_vector_type(8)));
typedef float f4v __attribute__((ext_vector_type(4)));
typedef unsigned short ushort_t;

__device__ inline unsigned short f2bf(float f) {
    union { float f; unsigned u; } v; v.f = f;
    unsigned r = v.u + 0x7fff + ((v.u >> 16) & 1);
    return (unsigned short)(r >> 16);
}
__device__ inline float bf2f(ushort_t u) {
    union { unsigned u; float f; } v; v.u = ((unsigned)u) << 16; return v.f;
}

#define GLOAD_LDS(gp, lp)                                              \
    __builtin_amdgcn_global_load_lds(                                  \
        (const __attribute__((address_space(1))) void*)(gp),           \
        (__attribute__((address_space(3))) void*)(lp), 16, 0, 0)

// ---------------------------------------------------------------------------
// Shared GEMM core: C_tile[64x128] accumulated over up to two operands.
// A row-major bf16 [M][K]; Bt row-major bf16 [N][K]. BK=32, double-buffered.
// LDS swizzle (involution within each 8-row group, canonical map
// physical = logical ^ ((logical_row & 7) << 4) bytes):
//   read  (logical r,c): r_p = r ^ ((r>>2)&1), c_p = c ^ (r&3)
//   stage (physical r,c): r_l = r ^ ((r>>2)&1), c_l = c ^ (r_l&3)
// global_load_lds dest stays linear; the SOURCE address is pre-swizzled.
// ---------------------------------------------------------------------------
__device__ __forceinline__ void gemm_core(
    const ushort_t* __restrict__ A1a, const ushort_t* __restrict__ A1b,
    int lda1, int K1, const ushort_t* __restrict__ B1t,
    const ushort_t* __restrict__ A2, int lda2, int K2,
    const ushort_t* __restrict__ B2t,
    int bm, int bn, ushort_t* lds, f4v acc[2][4])
{
    const int tid = threadIdx.x;
    const int wid = tid >> 6;
    const int lane = tid & 63;

    // staging geometry (physical): row srow, 16B chunk (lane&3)
    const int srow = wid * 16 + (lane >> 2);
    const int rl = srow ^ ((srow >> 2) & 1);            // logical row
    const int cle = (((lane & 3) ^ (rl & 3)) << 3);     // logical chunk, elems

    const int n1 = K1 >> 5;
    const int nt = n1 + (K2 >> 5);

    auto stage = [&](int buf, int t) {
        const ushort_t *Aa, *Ab, *Bt;
        int lda, ldb, k0;
        if (t < n1) { Aa = A1a; Ab = A1b; lda = lda1; Bt = B1t; ldb = K1; k0 = t * 32; }
        else        { Aa = A2; Ab = nullptr; lda = lda2; Bt = B2t; ldb = K2; k0 = (t - n1) * 32; }
        const int grow = bm + rl;
        const ushort_t* ap = (Ab != nullptr && grow >= 512)
                                 ? Ab + (size_t)(grow - 512) * lda + k0 + cle
                                 : Aa + (size_t)grow * lda + k0 + cle;
        GLOAD_LDS(ap, lds + buf * 6144 + wid * 512);
        const ushort_t* bp = Bt + (size_t)(bn + rl) * ldb + k0 + cle;
        GLOAD_LDS(bp, lds + buf * 6144 + 2048 + wid * 512);
        GLOAD_LDS(bp + (size_t)64 * ldb, lds + buf * 6144 + 4096 + wid * 512);
    };

    const int wr = wid >> 1, wc = wid & 1;
    const int lrow = lane & 15, lkg = lane >> 4;

    // physical fragment offsets (precomputed, loop-invariant)
    int aoff[2], boff[4];
#pragma unroll
    for (int m = 0; m < 2; ++m) {
        const int r = wr * 32 + m * 16 + lrow;
        aoff[m] = (r ^ ((r >> 2) & 1)) * 32 + ((lkg ^ (r & 3)) << 3);
    }
#pragma unroll
    for (int n = 0; n < 4; ++n) {
        const int r = wc * 64 + n * 16 + lrow;
        boff[n] = 2048 + (r ^ ((r >> 2) & 1)) * 32 + ((lkg ^ (r & 3)) << 3);
    }

    stage(0, 0);
    __syncthreads();
    int cur = 0;
    for (int t = 0; t < nt; ++t) {
        if (t + 1 < nt) stage(cur ^ 1, t + 1);
        const ushort_t* L = lds + cur * 6144;
        s8v af[2], bfv[4];
#pragma unroll
        for (int m = 0; m < 2; ++m) af[m] = *(const s8v*)(L + aoff[m]);
#pragma unroll
        for (int n = 0; n < 4; ++n) bfv[n] = *(const s8v*)(L + boff[n]);
#pragma unroll
        for (int m = 0; m < 2; ++m)
#pragma unroll
            for (int n = 0; n < 4; ++n)
                acc[m][n] = __builtin_amdgcn_mfma_f32_16x16x32_bf16(
                    af[m], bfv[n], acc[m][n], 0, 0, 0);
        __syncthreads();
        cur ^= 1;
    }
}

// ---------------------------------------------------------------------------
// Plain GEMM (single operand): C = act(A@Bt^T + bias). M%64==0, N%128==0.
// ---------------------------------------------------------------------------
template <int ACT>  // 0 none, 1 tanh
__global__ __launch_bounds__(256) void plain_gemm(
    const ushort_t* __restrict__ A, int lda, int K,
    const ushort_t* __restrict__ Bt,
    const float* __restrict__ bias, int bias_n,
    float* __restrict__ C, ushort_t* __restrict__ Cbf, int N)
{
    __shared__ __align__(16) ushort_t lds[2 * 6144];
    const int bm = blockIdx.x * 64, bn = blockIdx.y * 128;
    f4v acc[2][4] = {};
    gemm_core(A, nullptr, lda, K, Bt, nullptr, 0, 0, nullptr, bm, bn, lds, acc);

    const int tid = threadIdx.x, wid = tid >> 6, lane = tid & 63;
    const int wr = wid >> 1, wc = wid & 1, lrow = lane & 15, lkg = lane >> 4;
#pragma unroll
    for (int m = 0; m < 2; ++m) {
        const int row0 = bm + wr * 32 + m * 16 + lkg * 4;
#pragma unroll
        for (int n = 0; n < 4; ++n) {
            const int col = bn + wc * 64 + n * 16 + lrow;
            const float bv = (bias != nullptr && col < bias_n) ? bias[col] : 0.f;
#pragma unroll
            for (int r = 0; r < 4; ++r) {
                float v = acc[m][n][r] + bv;
                if (ACT == 1) v = tanhf(v);
                const size_t o = (size_t)(row0 + r) * N + col;
                if (C != nullptr) C[o] = v;
                if (Cbf != nullptr) Cbf[o] = f2bf(v);
            }
        }
    }
}

// ---------------------------------------------------------------------------
// Fused LSTM step: up to two independent problems (layer-1 of step s+1 and
// layer-2 of step s) in one launch, LSTM cell fused in the epilogue.
// N = 4096 gate-interleaved: col' = (j>>4)*64 + g*16 + (j&15).
// ---------------------------------------------------------------------------
struct Prob {
    const ushort_t* A1a; const ushort_t* A1b; int lda1; int K1;
    const ushort_t* B1t;
    const ushort_t* A2; int lda2; int K2; const ushort_t* B2t;
    const ushort_t* Dbf;   // bf16 [M][4096] pre-gates (incl. bias), or null
    const float* bias;     // fp32 [4096] permuted combined bias, or null
    float* cst;            // fp32 [M][1024] cell state (in/out)
    ushort_t* hout;        // bf16 [M][1024] new hidden (write buffer)
    ushort_t* hs;          // optional extra hidden dest
    int step_s;            // -1: identity; >=0: decoder hs mapping
};

__global__ __launch_bounds__(256) void lstm_step(Prob PA, int nxa, Prob PB)
{
    __shared__ __align__(16) ushort_t lds[2 * 6144];
    const int bx = blockIdx.x;
    const bool isA = bx < nxa;
    const Prob& P = isA ? PA : PB;
    const int bm = (isA ? bx : bx - nxa) * 64;
    const int bn = blockIdx.y * 128;

    f4v acc[2][4] = {};
    gemm_core(P.A1a, P.A1b, P.lda1, P.K1, P.B1t,
              P.A2, P.lda2, P.K2, P.B2t, bm, bn, lds, acc);

    const int tid = threadIdx.x, wid = tid >> 6, lane = tid & 63;
    const int wr = wid >> 1, wc = wid & 1, lrow = lane & 15, lkg = lane >> 4;
    const int colbase = bn + wc * 64;               // 64-aligned
    const int jb = (colbase >> 6) * 16 + lrow;      // hidden-unit index

#pragma unroll
    for (int m = 0; m < 2; ++m) {
        const int row0 = bm + wr * 32 + m * 16 + lkg * 4;
#pragma unroll
        for (int r = 0; r < 4; ++r) {
            const int row = row0 + r;
            float g0 = acc[m][0][r], g1 = acc[m][1][r];
            float g2 = acc[m][2][r], g3 = acc[m][3][r];
            if (P.Dbf != nullptr) {
                const ushort_t* d = P.Dbf + (size_t)row * 4096 + colbase + lrow;
                g0 += bf2f(d[0]); g1 += bf2f(d[16]); g2 += bf2f(d[32]); g3 += bf2f(d[48]);
            }
            if (P.bias != nullptr) {
                const float* b = P.bias + colbase + lrow;
                g0 += b[0]; g1 += b[16]; g2 += b[32]; g3 += b[48];
            }
            const size_t ci = (size_t)row * 1024 + jb;
            const float si = 1.f / (1.f + expf(-g0));
            const float sf = 1.f / (1.f + expf(-g1));
            const float so = 1.f / (1.f + expf(-g3));
            const float cn = fmaf(sf, P.cst[ci], si * tanhf(g2));
            const float hn = so * tanhf(cn);
            P.cst[ci] = cn;
            const ushort_t hb = f2bf(hn);
            P.hout[ci] = hb;
            if (P.hs != nullptr) {
                size_t d;
                if (P.step_s >= 0) {
                    const int u = row >> 9, b = row & 511;
                    d = ((size_t)((u * 16 + P.step_s) * 512 + b) << 10) + jb;
                } else {
                    d = ci;
                }
                P.hs[d] = hb;
            }
        }
    }
}

// ---------------------------------------------------------------------------
// Setup kernels
// ---------------------------------------------------------------------------
// out[n'][k] bf16 = in[k][n] fp32, zero-padded; PERM: gate-interleave n'.
template <int PERM>
__global__ __launch_bounds__(256) void transpose_to_bf16(
    const float* __restrict__ in, ushort_t* __restrict__ out,
    int K, int N, int Kp, int Np)
{
    __shared__ float tile[32][33];
    const int k0 = blockIdx.x * 32, n0 = blockIdx.y * 32;
    const int tx = threadIdx.x, ty = threadIdx.y;  // 32 x 8
#pragma unroll
    for (int q = 0; q < 4; ++q) {
        const int k = k0 + ty + 8 * q, n = n0 + tx;
        tile[ty + 8 * q][tx] = (k < K && n < N) ? in[(size_t)k * N + n] : 0.f;
    }
    __syncthreads();
#pragma unroll
    for (int q = 0; q < 4; ++q) {
        const int n = n0 + ty + 8 * q, k = k0 + tx;
        int np = n;
        if (PERM) np = ((n & 1023) >> 4) * 64 + (n >> 10) * 16 + (n & 15);
        out[(size_t)np * Kp + k] = f2bf(tile[tx][ty + 8 * q]);
    }
}

__global__ void convert_pad_bf16(const float* __restrict__ in,
                                 ushort_t* __restrict__ out,
                                 int K, int Kp, int total)
{
    const int idx = blockIdx.x * 256 + threadIdx.x;
    if (idx >= total) return;
    const int r = idx / Kp, k = idx - r * Kp;
    out[idx] = (k < K) ? f2bf(in[(size_t)r * K + k]) : (ushort_t)0;
}

__global__ void sos_init_bf16(ushort_t* __restrict__ sos)
{
    const int i = blockIdx.x * 256 + threadIdx.x;
    if (i < 512 * 288) sos[i] = ((i % 288) == 0) ? (ushort_t)0x3F80 : (ushort_t)0;
}

// out[col'] = b1[orig(col')] + b2[orig(col')]
__global__ void permute_bias(const float* __restrict__ b1,
                             const float* __restrict__ b2,
                             float* __restrict__ out)
{
    const int c = blockIdx.x * 256 + threadIdx.x;
    if (c >= 4096) return;
    const int g = (c >> 4) & 3;
    const int j = (c >> 6) * 16 + (c & 15);
    out[c] = b1[g * 1024 + j] + b2[g * 1024 + j];
}

// One block per row of logits [16384][384] (valid cols 0..257); row = t*512+b.
__global__ __launch_bounds__(256) void logsoftmax_kernel(
    const float* __restrict__ logits, float* __restrict__ out)
{
    const int row = blockIdx.x;
    const int tid = threadIdx.x;
    const float* L = logits + (size_t)row * 384;
    const int t = row >> 9;
    const int b = row & 511;
    float* O = out + ((size_t)b * 32 + t) * 258;

    const float x0 = L[tid];
    const float x1 = (tid < 2) ? L[256 + tid] : -1e30f;

    __shared__ float sm[4];
    float m = fmaxf(x0, x1);
#pragma unroll
    for (int off = 32; off > 0; off >>= 1) m = fmaxf(m, __shfl_down(m, off));
    if ((tid & 63) == 0) sm[tid >> 6] = m;
    __syncthreads();
    m = fmaxf(fmaxf(sm[0], sm[1]), fmaxf(sm[2], sm[3]));
    __syncthreads();

    float s = expf(x0 - m) + ((tid < 2) ? expf(x1 - m) : 0.f);
#pragma unroll
    for (int off = 32; off > 0; off >>= 1) s += __shfl_down(s, off);
    if ((tid & 63) == 0) sm[tid >> 6] = s;
    __syncthreads();
    s = sm[0] + sm[1] + sm[2] + sm[3];

    const float lse = m + logf(s);
    O[tid] = x0 - lse;
    if (tid < 2) O[256 + tid] = x1 - lse;
}

}  // namespace

extern "C" void kernel_launch(void* const* d_in, const int* in_sizes, int n_in,
                              void* d_out, int out_size, void* d_ws, size_t ws_size,
                              hipStream_t stream)
{
    (void)in_sizes; (void)n_in; (void)out_size; (void)ws_size;

    const float* z    = (const float*)d_in[0];
    const float* x    = (const float*)d_in[1];
    const float* cin  = (const float*)d_in[2];
    const float* ciW  = (const float*)d_in[3];
    const float* cib  = (const float*)d_in[4];
    const float* cW1i = (const float*)d_in[5];
    const float* cW1h = (const float*)d_in[6];
    const float* cb1i = (const float*)d_in[7];
    const float* cb1h = (const float*)d_in[8];
    const float* cW2i = (const float*)d_in[9];
    const float* cW2h = (const float*)d_in[10];
    const float* cb2i = (const float*)d_in[11];
    const float* cb2h = (const float*)d_in[12];
    const float* coW  = (const float*)d_in[13];
    const float* cob  = (const float*)d_in[14];
    const float* diW  = (const float*)d_in[15];
    const float* dib  = (const float*)d_in[16];
    const float* dW1i = (const float*)d_in[17];
    const float* dW1h = (const float*)d_in[18];
    const float* db1i = (const float*)d_in[19];
    const float* db1h = (const float*)d_in[20];
    const float* dW2i = (const float*)d_in[21];
    const float* dW2h = (const float*)d_in[22];
    const float* db2i = (const float*)d_in[23];
    const float* db2h = (const float*)d_in[24];
    const float* fcW  = (const float*)d_in[25];
    const float* fcb  = (const float*)d_in[26];
    float* out = (float*)d_out;

    // ---- workspace ----
    char* wsp = (char*)d_ws;
    size_t off = 0;
    auto allocf = [&](size_t n) { float* p = (float*)(wsp + off); off += n * 4; return p; };
    auto allocb = [&](size_t n) { ushort_t* p = (ushort_t*)(wsp + off); off += n * 2; return p; };

    // fp32: cell states (contiguous for one memset)
    float* cst = allocf((size_t)3 * 1024 * 1024 + 64);
    float* c1c = cst;
    float* c2c = cst + (size_t)512 * 1024;
    float* c1d = cst + (size_t)1024 * 1024;
    float* c2d = cst + (size_t)2 * 1024 * 1024;
    float* pb1c = allocf(4096);
    float* pb2c = allocf(4096);
    float* pb1d = allocf(4096);
    float* pb2d = allocf(4096);
    float* logits = allocf((size_t)16384 * 384);

    // bf16: h2 double-buffers (contiguous for one memset)
    ushort_t* h2z  = allocb((size_t)2 * (512 + 1024) * 1024);
    ushort_t* hc2A = h2z;
    ushort_t* hc2B = h2z + (size_t)512 * 1024;
    ushort_t* h2dA = h2z + (size_t)2 * 512 * 1024;
    ushort_t* h2dB = h2z + (size_t)(2 * 512 + 1024) * 1024;

    ushort_t* hc1A = allocb((size_t)512 * 1024);
    ushort_t* hc1B = allocb((size_t)512 * 1024);
    ushort_t* h1dA = allocb((size_t)1024 * 1024);
    ushort_t* h1dB = allocb((size_t)1024 * 1024);

    ushort_t* zbf    = allocb((size_t)512 * 512);
    ushort_t* cinbf  = allocb((size_t)512 * 288);
    ushort_t* sosbf  = allocb((size_t)512 * 288);
    ushort_t* xbf    = allocb((size_t)16384 * 288);
    ushort_t* chbf   = allocb((size_t)1024 * 1024);
    ushort_t* ccode  = allocb((size_t)1024 * 512);
    ushort_t* cpre   = allocb((size_t)1024 * 4096);  // bf16 pre-gates (perm, +bias)
    ushort_t* xW1c   = allocb((size_t)512 * 4096);   // bf16 pre-gates (perm, +bias)
    ushort_t* hsbf   = allocb((size_t)16384 * 1024);

    ushort_t* ciWt  = allocb((size_t)1024 * 512);
    ushort_t* cW1it = allocb((size_t)4096 * 288);
    ushort_t* cW1ht = allocb((size_t)4096 * 1024);
    ushort_t* cW2it = allocb((size_t)4096 * 1024);
    ushort_t* cW2ht = allocb((size_t)4096 * 1024);
    ushort_t* coWt  = allocb((size_t)512 * 1024);
    ushort_t* dtopt = allocb((size_t)4096 * 512);
    ushort_t* dbott = allocb((size_t)4096 * 288);
    ushort_t* diWt  = allocb((size_t)1024 * 512);
    ushort_t* dW1ht = allocb((size_t)4096 * 1024);
    ushort_t* dW2it = allocb((size_t)4096 * 1024);
    ushort_t* dW2ht = allocb((size_t)4096 * 1024);
    ushort_t* fcWt  = allocb((size_t)384 * 1024);

    hipMemsetAsync(cst, 0, (size_t)3 * 1024 * 1024 * 4, stream);
    hipMemsetAsync(h2z, 0, (size_t)2 * (512 + 1024) * 1024 * 2, stream);

    // ---- weight prep ----
    auto transp = [&](const float* in, ushort_t* o, int K, int N, int Kp, int Np, int perm) {
        dim3 g(Kp / 32, Np / 32), b(32, 8);
        if (perm) transpose_to_bf16<1><<<g, b, 0, stream>>>(in, o, K, N, Kp, Np);
        else      transpose_to_bf16<0><<<g, b, 0, stream>>>(in, o, K, N, Kp, Np);
    };
    transp(ciW, ciWt, 512, 1024, 512, 1024, 0);
    transp(cW1i, cW1it, 258, 4096, 288, 4096, 1);
    transp(cW1h, cW1ht, 1024, 4096, 1024, 4096, 1);
    transp(cW2i, cW2it, 1024, 4096, 1024, 4096, 1);
    transp(cW2h, cW2ht, 1024, 4096, 1024, 4096, 1);
    transp(coW, coWt, 1024, 512, 1024, 512, 0);
    transp(dW1i, dtopt, 512, 4096, 512, 4096, 1);
    transp(dW1i + (size_t)512 * 4096, dbott, 258, 4096, 288, 4096, 1);
    transp(diW, diWt, 512, 1024, 512, 1024, 0);
    transp(dW1h, dW1ht, 1024, 4096, 1024, 4096, 1);
    transp(dW2i, dW2it, 1024, 4096, 1024, 4096, 1);
    transp(dW2h, dW2ht, 1024, 4096, 1024, 4096, 1);
    transp(fcW, fcWt, 1024, 258, 1024, 384, 0);

    auto convert = [&](const float* in, ushort_t* o, int K, int Kp, int R) {
        const int total = R * Kp;
        convert_pad_bf16<<<dim3((total + 255) / 256), 256, 0, stream>>>(in, o, K, Kp, total);
    };
    convert(z, zbf, 512, 512, 512);
    convert(cin, cinbf, 258, 288, 512);
    convert(x, xbf, 258, 288, 16384);
    sos_init_bf16<<<dim3((512 * 288 + 255) / 256), 256, 0, stream>>>(sosbf);
    permute_bias<<<16, 256, 0, stream>>>(cb1i, cb1h, pb1c);
    permute_bias<<<16, 256, 0, stream>>>(cb2i, cb2h, pb2c);
    permute_bias<<<16, 256, 0, stream>>>(db1i, db1h, pb1d);
    permute_bias<<<16, 256, 0, stream>>>(db2i, db2h, pb2d);

    auto gemm = [&](int act, const ushort_t* A, int lda, int K, const ushort_t* Bt,
                    const float* bias, int bias_n,
                    float* C, ushort_t* Cbf, int M, int N) {
        dim3 g(M / 64, N / 128);
        if (act) plain_gemm<1><<<g, 256, 0, stream>>>(A, lda, K, Bt, bias, bias_n, C, Cbf, N);
        else     plain_gemm<0><<<g, 256, 0, stream>>>(A, lda, K, Bt, bias, bias_n, C, Cbf, N);
    };

    // ---- conductor init ----
    gemm(1, zbf, 512, 512, ciWt, cib, 1024, nullptr, hc1A, 512, 1024);
    gemm(0, cinbf, 288, 288, cW1it, pb1c, 4096, nullptr, xW1c, 512, 4096);

    // ---- conductor: 3 fused iterations (L1 at k=0,1; L2 at k=1,2) ----
    ushort_t* HC1[2] = {hc1A, hc1B};
    ushort_t* HC2[2] = {hc2A, hc2B};
    for (int k = 0; k <= 2; ++k) {
        Prob pa{}, pb{};
        int nxa = 0, nxb = 0;
        if (k < 2) {
            pa = {HC1[k & 1], nullptr, 1024, 1024, cW1ht,
                  nullptr, 0, 0, nullptr,
                  xW1c, nullptr, c1c, HC1[(k + 1) & 1], nullptr, -1};
            nxa = 8;
        }
        if (k >= 1) {
            pb = {HC1[k & 1], nullptr, 1024, 1024, cW2it,
                  HC2[k & 1], 1024, 1024, cW2ht,
                  nullptr, pb2c, c2c, HC2[(k + 1) & 1],
                  chbf + (size_t)(k - 1) * 512 * 1024, -1};
            nxb = 8;
        }
        lstm_step<<<dim3(nxa + nxb, 32), 256, 0, stream>>>(pa, nxa, pb);
    }

    // ---- codes + decoder init ----
    gemm(0, chbf, 1024, 1024, coWt, cob, 512, nullptr, ccode, 1024, 512);
    gemm(0, ccode, 512, 512, dtopt, pb1d, 4096, nullptr, cpre, 1024, 4096);
    gemm(1, ccode, 512, 512, diWt, dib, 1024, nullptr, h1dA, 1024, 1024);

    // ---- decoder: 17 fused iterations (L1 at k=0..15; L2 at k=1..16) ----
    ushort_t* H1[2] = {h1dA, h1dB};
    ushort_t* H2[2] = {h2dA, h2dB};
    for (int k = 0; k <= 16; ++k) {
        Prob pa{}, pb{};
        int nxa = 0, nxb = 0;
        if (k < 16) {
            const ushort_t* plo = (k == 0) ? sosbf : (xbf + (size_t)(k - 1) * 512 * 288);
            const ushort_t* phi = xbf + (size_t)(15 + k) * 512 * 288;
            pa = {plo, phi, 288, 288, dbott,
                  H1[k & 1], 1024, 1024, dW1ht,
                  cpre, nullptr, c1d, H1[(k + 1) & 1], nullptr, -1};
            nxa = 16;
        }
        if (k >= 1) {
            pb = {H1[k & 1], nullptr, 1024, 1024, dW2it,
                  H2[k & 1], 1024, 1024, dW2ht,
                  nullptr, pb2d, c2d, H2[(k + 1) & 1], hsbf, k - 1};
            nxb = 16;
        }
        lstm_step<<<dim3(nxa + nxb, 32), 256, 0, stream>>>(pa, nxa, pb);
    }

    // ---- projection + log_softmax ----
    gemm(0, hsbf, 1024, 1024, fcWt, fcb, 258, logits, nullptr, 16384, 384);
    logsoftmax_kernel<<<dim3(16384), 256, 0, stream>>>(logits, out);
}

// Round 4
// 1142.517 us; speedup vs baseline: 7.3632x; 1.1951x over previous
//
#include <hip/hip_runtime.h>
#include <cstddef>
#include <cstdint>

// Round 3: 128x128 MFMA tiles (32 MFMA/K-iter/wave), hoisted staging pointers,
// XCD-chunked block swizzle for L2 weight residency, fast-exp fused LSTM cell.

namespace {

typedef short s8v __attribute__((ext_vector_type(8)));
typedef float f4v __attribute__((ext_vector_type(4)));
typedef unsigned short ushort_t;

__device__ inline unsigned short f2bf(float f) {
    union { float f; unsigned u; } v; v.f = f;
    unsigned r = v.u + 0x7fff + ((v.u >> 16) & 1);
    return (unsigned short)(r >> 16);
}
__device__ inline float bf2f(ushort_t u) {
    union { unsigned u; float f; } v; v.u = ((unsigned)u) << 16; return v.f;
}
__device__ inline float sigm_f(float x) { return 1.f / (1.f + __expf(-x)); }
__device__ inline float tanh_f(float x) {
    const float e = __expf(2.f * fabsf(x));
    return copysignf(1.f - 2.f / (e + 1.f), x);
}

#define GLOAD_LDS(gp, lp)                                              \
    __builtin_amdgcn_global_load_lds(                                  \
        (const __attribute__((address_space(1))) void*)(gp),           \
        (__attribute__((address_space(3))) void*)(lp), 16, 0, 0)

// ---------------------------------------------------------------------------
// 128x128 GEMM core, BK=32, double-buffered LDS (32 KB), swizzled reads.
// A row-major bf16 [M][K]; Bt row-major bf16 [N][K]. acc[4][4] per wave.
// Swizzle involution (16B chunks within 8-row groups):
//   physical(r,chunk) <-> logical(r ^ ((r>>2)&1), chunk ^ (r_logical&3))
// global_load_lds dest stays linear; SOURCE address pre-swizzled.
// ---------------------------------------------------------------------------
__device__ __forceinline__ void gemm_core(
    const ushort_t* __restrict__ A1a, const ushort_t* __restrict__ A1b,
    int lda1, int K1, const ushort_t* __restrict__ B1t,
    const ushort_t* __restrict__ A2, int lda2, int K2,
    const ushort_t* __restrict__ B2t,
    int bm, int bn, ushort_t* lds, f4v acc[4][4])
{
    const int tid = threadIdx.x;
    const int wid = tid >> 6;
    const int lane = tid & 63;

    // staging geometry: two issues per matrix (rows 0-63, 64-127)
    const int sr0 = wid * 16 + (lane >> 2);
    const int sr1 = sr0 + 64;
    const int rl0 = sr0 ^ ((sr0 >> 2) & 1);
    const int rl1 = sr1 ^ ((sr1 >> 2) & 1);
    const int c0 = (((lane & 3) ^ (rl0 & 3)) << 3);  // elems
    const int c1 = (((lane & 3) ^ (rl1 & 3)) << 3);
    const int ldst = wid * 512;  // per-wave 1KB chunk in elems

    auto arow = [&](const ushort_t* Aa, const ushort_t* Ab, int lda,
                    int r) -> const ushort_t* {
        return (Ab != nullptr && r >= 512) ? Ab + (size_t)(r - 512) * lda
                                           : Aa + (size_t)r * lda;
    };
    const ushort_t* a0 = arow(A1a, A1b, lda1, bm + rl0) + c0;
    const ushort_t* a1 = arow(A1a, A1b, lda1, bm + rl1) + c1;
    const ushort_t* b0 = B1t + (size_t)(bn + rl0) * K1 + c0;
    const ushort_t* b1 = B1t + (size_t)(bn + rl1) * K1 + c1;

    auto stage = [&](int buf) {
        ushort_t* Lb = lds + buf * 8192;
        GLOAD_LDS(a0, Lb + ldst);
        GLOAD_LDS(a1, Lb + 2048 + ldst);
        GLOAD_LDS(b0, Lb + 4096 + ldst);
        GLOAD_LDS(b1, Lb + 6144 + ldst);
        a0 += 32; a1 += 32; b0 += 32; b1 += 32;
    };

    // fragment read offsets (physical, loop-invariant)
    const int wr = wid >> 1, wc = wid & 1;
    const int lrow = lane & 15, lkg = lane >> 4;
    int aoff[4], boff[4];
#pragma unroll
    for (int m = 0; m < 4; ++m) {
        const int r = wr * 64 + m * 16 + lrow;
        aoff[m] = (r ^ ((r >> 2) & 1)) * 32 + ((lkg ^ (r & 3)) << 3);
    }
#pragma unroll
    for (int n = 0; n < 4; ++n) {
        const int r = wc * 64 + n * 16 + lrow;
        boff[n] = 4096 + (r ^ ((r >> 2) & 1)) * 32 + ((lkg ^ (r & 3)) << 3);
    }

    auto compute = [&](int buf) {
        const ushort_t* L = lds + buf * 8192;
        s8v af[4], bv[4];
#pragma unroll
        for (int m = 0; m < 4; ++m) af[m] = *(const s8v*)(L + aoff[m]);
#pragma unroll
        for (int n = 0; n < 4; ++n) bv[n] = *(const s8v*)(L + boff[n]);
#pragma unroll
        for (int m = 0; m < 4; ++m)
#pragma unroll
            for (int n = 0; n < 4; ++n)
                acc[m][n] = __builtin_amdgcn_mfma_f32_16x16x32_bf16(
                    af[m], bv[n], acc[m][n], 0, 0, 0);
    };

    const int n1 = K1 >> 5, n2 = K2 >> 5;
    stage(0);
    __syncthreads();
    int cur = 0;
    for (int t = 0; t < n1; ++t) {
        if (t + 1 < n1) {
            stage(cur ^ 1);
        } else if (n2 > 0) {
            a0 = A2 + (size_t)(bm + rl0) * lda2 + c0;
            a1 = A2 + (size_t)(bm + rl1) * lda2 + c1;
            b0 = B2t + (size_t)(bn + rl0) * K2 + c0;
            b1 = B2t + (size_t)(bn + rl1) * K2 + c1;
            stage(cur ^ 1);
        }
        compute(cur);
        __syncthreads();
        cur ^= 1;
    }
    for (int t = 0; t < n2; ++t) {
        if (t + 1 < n2) stage(cur ^ 1);
        compute(cur);
        __syncthreads();
        cur ^= 1;
    }
}

// ---------------------------------------------------------------------------
// Plain GEMM: C = act(A@Bt^T + bias). M%128==0, N%128==0.
// ---------------------------------------------------------------------------
template <int ACT>  // 0 none, 1 tanh
__global__ __launch_bounds__(256) void plain_gemm(
    const ushort_t* __restrict__ A, int lda, int K,
    const ushort_t* __restrict__ Bt,
    const float* __restrict__ bias, int bias_n,
    float* __restrict__ C, ushort_t* __restrict__ Cbf, int N)
{
    __shared__ __align__(16) ushort_t lds[2 * 8192];
    const int bm = blockIdx.x * 128, bn = blockIdx.y * 128;
    f4v acc[4][4] = {};
    gemm_core(A, nullptr, lda, K, Bt, nullptr, 0, 0, nullptr, bm, bn, lds, acc);

    const int tid = threadIdx.x, wid = tid >> 6, lane = tid & 63;
    const int wr = wid >> 1, wc = wid & 1, lrow = lane & 15, lkg = lane >> 4;
#pragma unroll
    for (int m = 0; m < 4; ++m) {
        const int row0 = bm + wr * 64 + m * 16 + lkg * 4;
#pragma unroll
        for (int n = 0; n < 4; ++n) {
            const int col = bn + wc * 64 + n * 16 + lrow;
            const float bv = (bias != nullptr && col < bias_n) ? bias[col] : 0.f;
#pragma unroll
            for (int r = 0; r < 4; ++r) {
                float v = acc[m][n][r] + bv;
                if (ACT == 1) v = tanh_f(v);
                const size_t o = (size_t)(row0 + r) * N + col;
                if (C != nullptr) C[o] = v;
                if (Cbf != nullptr) Cbf[o] = f2bf(v);
            }
        }
    }
}

// ---------------------------------------------------------------------------
// Fused LSTM step: two independent problems (L1 of step s+1 and L2 of step s),
// LSTM cell fused in epilogue. Weights gate-interleaved:
// col' = (j>>4)*64 + g*16 + (j&15).  1D grid, XCD-chunked swizzle.
// ---------------------------------------------------------------------------
struct Prob {
    const ushort_t* A1a; const ushort_t* A1b; int lda1; int K1;
    const ushort_t* B1t;
    const ushort_t* A2; int lda2; int K2; const ushort_t* B2t;
    const ushort_t* Dbf;   // bf16 [M][4096] pre-gates (incl. bias), or null
    const float* bias;     // fp32 [4096] permuted combined bias, or null
    float* cst;            // fp32 [M][1024] cell state (in/out)
    ushort_t* hout;        // bf16 [M][1024] new hidden
    ushort_t* hs;          // optional extra hidden dest
    int step_s;            // -1: identity; >=0: decoder hs mapping
};

__global__ __launch_bounds__(256) void lstm_step(Prob PA, int nxa, Prob PB,
                                                 int mshift)
{
    __shared__ __align__(16) ushort_t lds[2 * 8192];
    // XCD-chunked swizzle: each XCD gets a contiguous chunk (few N-panels).
    const int nblk = gridDim.x;
    const int wg = blockIdx.x;
    const int swz = (wg & 7) * (nblk >> 3) + (wg >> 3);
    const int nmb = 1 << mshift;
    const int nb = swz >> mshift;
    const int mb = swz & (nmb - 1);

    const bool isA = mb < nxa;
    const Prob& P = isA ? PA : PB;
    const int bm = (isA ? mb : mb - nxa) * 128;
    const int bn = nb * 128;

    f4v acc[4][4] = {};
    gemm_core(P.A1a, P.A1b, P.lda1, P.K1, P.B1t,
              P.A2, P.lda2, P.K2, P.B2t, bm, bn, lds, acc);

    const int tid = threadIdx.x, wid = tid >> 6, lane = tid & 63;
    const int wr = wid >> 1, wc = wid & 1, lrow = lane & 15, lkg = lane >> 4;
    const int colbase = bn + wc * 64;           // 64-aligned
    const int jb = (colbase >> 6) * 16 + lrow;  // hidden-unit index

#pragma unroll
    for (int m = 0; m < 4; ++m) {
        const int row0 = bm + wr * 64 + m * 16 + lkg * 4;
#pragma unroll
        for (int r = 0; r < 4; ++r) {
            const int row = row0 + r;
            float g0 = acc[m][0][r], g1 = acc[m][1][r];
            float g2 = acc[m][2][r], g3 = acc[m][3][r];
            if (P.Dbf != nullptr) {
                const ushort_t* d = P.Dbf + (size_t)row * 4096 + colbase + lrow;
                g0 += bf2f(d[0]); g1 += bf2f(d[16]);
                g2 += bf2f(d[32]); g3 += bf2f(d[48]);
            }
            if (P.bias != nullptr) {
                const float* b = P.bias + colbase + lrow;
                g0 += b[0]; g1 += b[16]; g2 += b[32]; g3 += b[48];
            }
            const size_t ci = (size_t)row * 1024 + jb;
            const float cn = fmaf(sigm_f(g1), P.cst[ci], sigm_f(g0) * tanh_f(g2));
            const float hn = sigm_f(g3) * tanh_f(cn);
            P.cst[ci] = cn;
            const ushort_t hb = f2bf(hn);
            P.hout[ci] = hb;
            if (P.hs != nullptr) {
                size_t d;
                if (P.step_s >= 0) {
                    const int u = row >> 9, b = row & 511;
                    d = ((size_t)((u * 16 + P.step_s) * 512 + b) << 10) + jb;
                } else {
                    d = ci;
                }
                P.hs[d] = hb;
            }
        }
    }
}

// ---------------------------------------------------------------------------
// Setup kernels
// ---------------------------------------------------------------------------
template <int PERM>
__global__ __launch_bounds__(256) void transpose_to_bf16(
    const float* __restrict__ in, ushort_t* __restrict__ out,
    int K, int N, int Kp, int Np)
{
    __shared__ float tile[32][33];
    const int k0 = blockIdx.x * 32, n0 = blockIdx.y * 32;
    const int tx = threadIdx.x, ty = threadIdx.y;  // 32 x 8
#pragma unroll
    for (int q = 0; q < 4; ++q) {
        const int k = k0 + ty + 8 * q, n = n0 + tx;
        tile[ty + 8 * q][tx] = (k < K && n < N) ? in[(size_t)k * N + n] : 0.f;
    }
    __syncthreads();
#pragma unroll
    for (int q = 0; q < 4; ++q) {
        const int n = n0 + ty + 8 * q, k = k0 + tx;
        int np = n;
        if (PERM) np = ((n & 1023) >> 4) * 64 + (n >> 10) * 16 + (n & 15);
        out[(size_t)np * Kp + k] = f2bf(tile[tx][ty + 8 * q]);
    }
}

__global__ void convert_pad_bf16(const float* __restrict__ in,
                                 ushort_t* __restrict__ out,
                                 int K, int Kp, int total)
{
    const int idx = blockIdx.x * 256 + threadIdx.x;
    if (idx >= total) return;
    const int r = idx / Kp, k = idx - r * Kp;
    out[idx] = (k < K) ? f2bf(in[(size_t)r * K + k]) : (ushort_t)0;
}

__global__ void sos_init_bf16(ushort_t* __restrict__ sos)
{
    const int i = blockIdx.x * 256 + threadIdx.x;
    if (i < 512 * 288) sos[i] = ((i % 288) == 0) ? (ushort_t)0x3F80 : (ushort_t)0;
}

__global__ void permute_bias(const float* __restrict__ b1,
                             const float* __restrict__ b2,
                             float* __restrict__ out)
{
    const int c = blockIdx.x * 256 + threadIdx.x;
    if (c >= 4096) return;
    const int g = (c >> 4) & 3;
    const int j = (c >> 6) * 16 + (c & 15);
    out[c] = b1[g * 1024 + j] + b2[g * 1024 + j];
}

// One block per row of logits [16384][384] (valid cols 0..257); row = t*512+b.
__global__ __launch_bounds__(256) void logsoftmax_kernel(
    const float* __restrict__ logits, float* __restrict__ out)
{
    const int row = blockIdx.x;
    const int tid = threadIdx.x;
    const float* L = logits + (size_t)row * 384;
    const int t = row >> 9;
    const int b = row & 511;
    float* O = out + ((size_t)b * 32 + t) * 258;

    const float x0 = L[tid];
    const float x1 = (tid < 2) ? L[256 + tid] : -1e30f;

    __shared__ float sm[4];
    float m = fmaxf(x0, x1);
#pragma unroll
    for (int off = 32; off > 0; off >>= 1) m = fmaxf(m, __shfl_down(m, off));
    if ((tid & 63) == 0) sm[tid >> 6] = m;
    __syncthreads();
    m = fmaxf(fmaxf(sm[0], sm[1]), fmaxf(sm[2], sm[3]));
    __syncthreads();

    float s = expf(x0 - m) + ((tid < 2) ? expf(x1 - m) : 0.f);
#pragma unroll
    for (int off = 32; off > 0; off >>= 1) s += __shfl_down(s, off);
    if ((tid & 63) == 0) sm[tid >> 6] = s;
    __syncthreads();
    s = sm[0] + sm[1] + sm[2] + sm[3];

    const float lse = m + logf(s);
    O[tid] = x0 - lse;
    if (tid < 2) O[256 + tid] = x1 - lse;
}

}  // namespace

extern "C" void kernel_launch(void* const* d_in, const int* in_sizes, int n_in,
                              void* d_out, int out_size, void* d_ws, size_t ws_size,
                              hipStream_t stream)
{
    (void)in_sizes; (void)n_in; (void)out_size; (void)ws_size;

    const float* z    = (const float*)d_in[0];
    const float* x    = (const float*)d_in[1];
    const float* cin  = (const float*)d_in[2];
    const float* ciW  = (const float*)d_in[3];
    const float* cib  = (const float*)d_in[4];
    const float* cW1i = (const float*)d_in[5];
    const float* cW1h = (const float*)d_in[6];
    const float* cb1i = (const float*)d_in[7];
    const float* cb1h = (const float*)d_in[8];
    const float* cW2i = (const float*)d_in[9];
    const float* cW2h = (const float*)d_in[10];
    const float* cb2i = (const float*)d_in[11];
    const float* cb2h = (const float*)d_in[12];
    const float* coW  = (const float*)d_in[13];
    const float* cob  = (const float*)d_in[14];
    const float* diW  = (const float*)d_in[15];
    const float* dib  = (const float*)d_in[16];
    const float* dW1i = (const float*)d_in[17];
    const float* dW1h = (const float*)d_in[18];
    const float* db1i = (const float*)d_in[19];
    const float* db1h = (const float*)d_in[20];
    const float* dW2i = (const float*)d_in[21];
    const float* dW2h = (const float*)d_in[22];
    const float* db2i = (const float*)d_in[23];
    const float* db2h = (const float*)d_in[24];
    const float* fcW  = (const float*)d_in[25];
    const float* fcb  = (const float*)d_in[26];
    float* out = (float*)d_out;

    // ---- workspace ----
    char* wsp = (char*)d_ws;
    size_t off = 0;
    auto allocf = [&](size_t n) { float* p = (float*)(wsp + off); off += n * 4; return p; };
    auto allocb = [&](size_t n) { ushort_t* p = (ushort_t*)(wsp + off); off += n * 2; return p; };

    float* cst = allocf((size_t)3 * 1024 * 1024 + 64);
    float* c1c = cst;
    float* c2c = cst + (size_t)512 * 1024;
    float* c1d = cst + (size_t)1024 * 1024;
    float* c2d = cst + (size_t)2 * 1024 * 1024;
    float* pb1c = allocf(4096);
    float* pb2c = allocf(4096);
    float* pb1d = allocf(4096);
    float* pb2d = allocf(4096);
    float* logits = allocf((size_t)16384 * 384);

    ushort_t* h2z  = allocb((size_t)2 * (512 + 1024) * 1024);
    ushort_t* hc2A = h2z;
    ushort_t* hc2B = h2z + (size_t)512 * 1024;
    ushort_t* h2dA = h2z + (size_t)2 * 512 * 1024;
    ushort_t* h2dB = h2z + (size_t)(2 * 512 + 1024) * 1024;

    ushort_t* hc1A = allocb((size_t)512 * 1024);
    ushort_t* hc1B = allocb((size_t)512 * 1024);
    ushort_t* h1dA = allocb((size_t)1024 * 1024);
    ushort_t* h1dB = allocb((size_t)1024 * 1024);

    ushort_t* zbf    = allocb((size_t)512 * 512);
    ushort_t* cinbf  = allocb((size_t)512 * 288);
    ushort_t* sosbf  = allocb((size_t)512 * 288);
    ushort_t* xbf    = allocb((size_t)16384 * 288);
    ushort_t* chbf   = allocb((size_t)1024 * 1024);
    ushort_t* ccode  = allocb((size_t)1024 * 512);
    ushort_t* cpre   = allocb((size_t)1024 * 4096);
    ushort_t* xW1c   = allocb((size_t)512 * 4096);
    ushort_t* hsbf   = allocb((size_t)16384 * 1024);

    ushort_t* ciWt  = allocb((size_t)1024 * 512);
    ushort_t* cW1it = allocb((size_t)4096 * 288);
    ushort_t* cW1ht = allocb((size_t)4096 * 1024);
    ushort_t* cW2it = allocb((size_t)4096 * 1024);
    ushort_t* cW2ht = allocb((size_t)4096 * 1024);
    ushort_t* coWt  = allocb((size_t)512 * 1024);
    ushort_t* dtopt = allocb((size_t)4096 * 512);
    ushort_t* dbott = allocb((size_t)4096 * 288);
    ushort_t* diWt  = allocb((size_t)1024 * 512);
    ushort_t* dW1ht = allocb((size_t)4096 * 1024);
    ushort_t* dW2it = allocb((size_t)4096 * 1024);
    ushort_t* dW2ht = allocb((size_t)4096 * 1024);
    ushort_t* fcWt  = allocb((size_t)384 * 1024);

    hipMemsetAsync(cst, 0, (size_t)3 * 1024 * 1024 * 4, stream);
    hipMemsetAsync(h2z, 0, (size_t)2 * (512 + 1024) * 1024 * 2, stream);

    // ---- weight prep ----
    auto transp = [&](const float* in, ushort_t* o, int K, int N, int Kp, int Np, int perm) {
        dim3 g(Kp / 32, Np / 32), b(32, 8);
        if (perm) transpose_to_bf16<1><<<g, b, 0, stream>>>(in, o, K, N, Kp, Np);
        else      transpose_to_bf16<0><<<g, b, 0, stream>>>(in, o, K, N, Kp, Np);
    };
    transp(ciW, ciWt, 512, 1024, 512, 1024, 0);
    transp(cW1i, cW1it, 258, 4096, 288, 4096, 1);
    transp(cW1h, cW1ht, 1024, 4096, 1024, 4096, 1);
    transp(cW2i, cW2it, 1024, 4096, 1024, 4096, 1);
    transp(cW2h, cW2ht, 1024, 4096, 1024, 4096, 1);
    transp(coW, coWt, 1024, 512, 1024, 512, 0);
    transp(dW1i, dtopt, 512, 4096, 512, 4096, 1);
    transp(dW1i + (size_t)512 * 4096, dbott, 258, 4096, 288, 4096, 1);
    transp(diW, diWt, 512, 1024, 512, 1024, 0);
    transp(dW1h, dW1ht, 1024, 4096, 1024, 4096, 1);
    transp(dW2i, dW2it, 1024, 4096, 1024, 4096, 1);
    transp(dW2h, dW2ht, 1024, 4096, 1024, 4096, 1);
    transp(fcW, fcWt, 1024, 258, 1024, 384, 0);

    auto convert = [&](const float* in, ushort_t* o, int K, int Kp, int R) {
        const int total = R * Kp;
        convert_pad_bf16<<<dim3((total + 255) / 256), 256, 0, stream>>>(in, o, K, Kp, total);
    };
    convert(z, zbf, 512, 512, 512);
    convert(cin, cinbf, 258, 288, 512);
    convert(x, xbf, 258, 288, 16384);
    sos_init_bf16<<<dim3((512 * 288 + 255) / 256), 256, 0, stream>>>(sosbf);
    permute_bias<<<16, 256, 0, stream>>>(cb1i, cb1h, pb1c);
    permute_bias<<<16, 256, 0, stream>>>(cb2i, cb2h, pb2c);
    permute_bias<<<16, 256, 0, stream>>>(db1i, db1h, pb1d);
    permute_bias<<<16, 256, 0, stream>>>(db2i, db2h, pb2d);

    auto gemm = [&](int act, const ushort_t* A, int lda, int K, const ushort_t* Bt,
                    const float* bias, int bias_n,
                    float* C, ushort_t* Cbf, int M, int N) {
        dim3 g(M / 128, N / 128);
        if (act) plain_gemm<1><<<g, 256, 0, stream>>>(A, lda, K, Bt, bias, bias_n, C, Cbf, N);
        else     plain_gemm<0><<<g, 256, 0, stream>>>(A, lda, K, Bt, bias, bias_n, C, Cbf, N);
    };

    // ---- conductor init ----
    gemm(1, zbf, 512, 512, ciWt, cib, 1024, nullptr, hc1A, 512, 1024);
    gemm(0, cinbf, 288, 288, cW1it, pb1c, 4096, nullptr, xW1c, 512, 4096);

    // ---- conductor: 3 fused iterations (L1 at k=0,1; L2 at k=1,2) ----
    ushort_t* HC1[2] = {hc1A, hc1B};
    ushort_t* HC2[2] = {hc2A, hc2B};
    for (int k = 0; k <= 2; ++k) {
        Prob pa{}, pb{};
        int nxa = 0, nxb = 0;
        if (k < 2) {
            pa = {HC1[k & 1], nullptr, 1024, 1024, cW1ht,
                  nullptr, 0, 0, nullptr,
                  xW1c, nullptr, c1c, HC1[(k + 1) & 1], nullptr, -1};
            nxa = 4;
        }
        if (k >= 1) {
            pb = {HC1[k & 1], nullptr, 1024, 1024, cW2it,
                  HC2[k & 1], 1024, 1024, cW2ht,
                  nullptr, pb2c, c2c, HC2[(k + 1) & 1],
                  chbf + (size_t)(k - 1) * 512 * 1024, -1};
            nxb = 4;
        }
        const int nmb = nxa + nxb;               // 4 or 8 (power of 2)
        const int mshift = (nmb == 4) ? 2 : 3;
        lstm_step<<<dim3(nmb * 32), 256, 0, stream>>>(pa, nxa, pb, mshift);
    }

    // ---- codes + decoder init ----
    gemm(0, chbf, 1024, 1024, coWt, cob, 512, nullptr, ccode, 1024, 512);
    gemm(0, ccode, 512, 512, dtopt, pb1d, 4096, nullptr, cpre, 1024, 4096);
    gemm(1, ccode, 512, 512, diWt, dib, 1024, nullptr, h1dA, 1024, 1024);

    // ---- decoder: 17 fused iterations (L1 at k=0..15; L2 at k=1..16) ----
    ushort_t* H1[2] = {h1dA, h1dB};
    ushort_t* H2[2] = {h2dA, h2dB};
    for (int k = 0; k <= 16; ++k) {
        Prob pa{}, pb{};
        int nxa = 0, nxb = 0;
        if (k < 16) {
            const ushort_t* plo = (k == 0) ? sosbf : (xbf + (size_t)(k - 1) * 512 * 288);
            const ushort_t* phi = xbf + (size_t)(15 + k) * 512 * 288;
            pa = {plo, phi, 288, 288, dbott,
                  H1[k & 1], 1024, 1024, dW1ht,
                  cpre, nullptr, c1d, H1[(k + 1) & 1], nullptr, -1};
            nxa = 8;
        }
        if (k >= 1) {
            pb = {H1[k & 1], nullptr, 1024, 1024, dW2it,
                  H2[k & 1], 1024, 1024, dW2ht,
                  nullptr, pb2d, c2d, H2[(k + 1) & 1], hsbf, k - 1};
            nxb = 8;
        }
        const int nmb = nxa + nxb;               // 8 or 16
        const int mshift = (nmb == 8) ? 3 : 4;
        lstm_step<<<dim3(nmb * 32), 256, 0, stream>>>(pa, nxa, pb, mshift);
    }

    // ---- projection + log_softmax ----
    gemm(0, hsbf, 1024, 1024, fcWt, fcb, 258, logits, nullptr, 16384, 384);
    logsoftmax_kernel<<<dim3(16384), 256, 0, stream>>>(logits, out);
}

// Round 5
// 1108.289 us; speedup vs baseline: 7.5906x; 1.0309x over previous
//
#include <hip/hip_runtime.h>
#include <cstddef>
#include <cstdint>

// Round 4: counted-vmcnt software pipeline (depth 2, 3 LDS buffers) in the
// GEMM core: {vmcnt(4); s_barrier; stage(t+2); ds_read; setprio(1) MFMA}.
// Loads stay in flight across barriers (T3/T4); setprio on MFMA cluster (T5).

namespace {

typedef short s8v __attribute__((ext_vector_type(8)));
typedef float f4v __attribute__((ext_vector_type(4)));
typedef unsigned short ushort_t;

__device__ inline unsigned short f2bf(float f) {
    union { float f; unsigned u; } v; v.f = f;
    unsigned r = v.u + 0x7fff + ((v.u >> 16) & 1);
    return (unsigned short)(r >> 16);
}
__device__ inline float bf2f(ushort_t u) {
    union { unsigned u; float f; } v; v.u = ((unsigned)u) << 16; return v.f;
}
__device__ inline float sigm_f(float x) { return 1.f / (1.f + __expf(-x)); }
__device__ inline float tanh_f(float x) {
    const float e = __expf(2.f * fabsf(x));
    return copysignf(1.f - 2.f / (e + 1.f), x);
}

#define GLOAD_LDS(gp, lp)                                              \
    __builtin_amdgcn_global_load_lds(                                  \
        (const __attribute__((address_space(1))) void*)(gp),           \
        (__attribute__((address_space(3))) void*)(lp), 16, 0, 0)

// ---------------------------------------------------------------------------
// 128x128 GEMM core, BK=32, 3-buffer LDS pipeline (prefetch depth 2).
// A row-major bf16 [M][K]; Bt row-major bf16 [N][K]. acc[4][4] per wave.
// Swizzle involution (16B chunks within 8-row groups):
//   physical(r,chunk) <-> logical(r ^ ((r>>2)&1), chunk ^ (r_logical&3))
// global_load_lds dest stays linear; SOURCE address pre-swizzled.
// Pipeline ledger (per wave, 4 loads per stage): after prologue 8 in
// flight; per iter: vmcnt(4) releases tile t, barrier, issue tile t+2.
// Buf (t+2)%3 was last ds_read in iter t-1 (lgkmcnt before its MFMAs,
// which precede this barrier) -> no overwrite race.
// ---------------------------------------------------------------------------
__device__ __forceinline__ void gemm_core(
    const ushort_t* __restrict__ A1a, const ushort_t* __restrict__ A1b,
    int lda1, int K1, const ushort_t* __restrict__ B1t,
    const ushort_t* __restrict__ A2, int lda2, int K2,
    const ushort_t* __restrict__ B2t,
    int bm, int bn, ushort_t* lds, f4v acc[4][4])
{
    const int tid = threadIdx.x;
    const int wid = tid >> 6;
    const int lane = tid & 63;

    // staging geometry: two issues per matrix (rows 0-63, 64-127)
    const int sr0 = wid * 16 + (lane >> 2);
    const int sr1 = sr0 + 64;
    const int rl0 = sr0 ^ ((sr0 >> 2) & 1);
    const int rl1 = sr1 ^ ((sr1 >> 2) & 1);
    const int c0 = (((lane & 3) ^ (rl0 & 3)) << 3);  // elems
    const int c1 = (((lane & 3) ^ (rl1 & 3)) << 3);
    const int ldst = wid * 512;  // per-wave 1KB chunk in elems

    auto arow = [&](const ushort_t* Aa, const ushort_t* Ab, int lda,
                    int r) -> const ushort_t* {
        return (Ab != nullptr && r >= 512) ? Ab + (size_t)(r - 512) * lda
                                           : Aa + (size_t)r * lda;
    };
    const ushort_t* a1r0 = arow(A1a, A1b, lda1, bm + rl0) + c0;
    const ushort_t* a1r1 = arow(A1a, A1b, lda1, bm + rl1) + c1;
    const ushort_t* b1r0 = B1t + (size_t)(bn + rl0) * K1 + c0;
    const ushort_t* b1r1 = B1t + (size_t)(bn + rl1) * K1 + c1;
    const int n1 = K1 >> 5, n2 = (B2t != nullptr) ? (K2 >> 5) : 0;
    const int nt = n1 + n2;
    const ushort_t* a2r0 = nullptr; const ushort_t* a2r1 = nullptr;
    const ushort_t* b2r0 = nullptr; const ushort_t* b2r1 = nullptr;
    if (n2 > 0) {
        a2r0 = A2 + (size_t)(bm + rl0) * lda2 + c0;
        a2r1 = A2 + (size_t)(bm + rl1) * lda2 + c1;
        b2r0 = B2t + (size_t)(bn + rl0) * K2 + c0;
        b2r1 = B2t + (size_t)(bn + rl1) * K2 + c1;
    }

    auto stage = [&](int idx, int buf) {
        ushort_t* Lb = lds + buf * 8192;
        const ushort_t *pa0, *pa1, *pb0, *pb1;
        if (idx < n1) {
            const int k0 = idx << 5;
            pa0 = a1r0 + k0; pa1 = a1r1 + k0; pb0 = b1r0 + k0; pb1 = b1r1 + k0;
        } else {
            const int k0 = (idx - n1) << 5;
            pa0 = a2r0 + k0; pa1 = a2r1 + k0; pb0 = b2r0 + k0; pb1 = b2r1 + k0;
        }
        GLOAD_LDS(pa0, Lb + ldst);
        GLOAD_LDS(pa1, Lb + 2048 + ldst);
        GLOAD_LDS(pb0, Lb + 4096 + ldst);
        GLOAD_LDS(pb1, Lb + 6144 + ldst);
    };

    // fragment read offsets (physical, loop-invariant)
    const int wr = wid >> 1, wc = wid & 1;
    const int lrow = lane & 15, lkg = lane >> 4;
    int aoff[4], boff[4];
#pragma unroll
    for (int m = 0; m < 4; ++m) {
        const int r = wr * 64 + m * 16 + lrow;
        aoff[m] = (r ^ ((r >> 2) & 1)) * 32 + ((lkg ^ (r & 3)) << 3);
    }
#pragma unroll
    for (int n = 0; n < 4; ++n) {
        const int r = wc * 64 + n * 16 + lrow;
        boff[n] = 4096 + (r ^ ((r >> 2) & 1)) * 32 + ((lkg ^ (r & 3)) << 3);
    }

    stage(0, 0);
    stage(1, 1);
    int sbuf = 2, cbuf = 0;
    for (int t = 0; t < nt; ++t) {
        if (t == nt - 1) {
            asm volatile("s_waitcnt vmcnt(0)" ::: "memory");
        } else {
            asm volatile("s_waitcnt vmcnt(4)" ::: "memory");
        }
        __builtin_amdgcn_s_barrier();
        __builtin_amdgcn_sched_barrier(0);
        if (t + 2 < nt) {
            stage(t + 2, sbuf);
            sbuf = (sbuf == 2) ? 0 : sbuf + 1;
        }
        const ushort_t* L = lds + cbuf * 8192;
        s8v af[4], bv[4];
#pragma unroll
        for (int m = 0; m < 4; ++m) af[m] = *(const s8v*)(L + aoff[m]);
#pragma unroll
        for (int n = 0; n < 4; ++n) bv[n] = *(const s8v*)(L + boff[n]);
        __builtin_amdgcn_s_setprio(1);
#pragma unroll
        for (int m = 0; m < 4; ++m)
#pragma unroll
            for (int n = 0; n < 4; ++n)
                acc[m][n] = __builtin_amdgcn_mfma_f32_16x16x32_bf16(
                    af[m], bv[n], acc[m][n], 0, 0, 0);
        __builtin_amdgcn_s_setprio(0);
        cbuf = (cbuf == 2) ? 0 : cbuf + 1;
    }
}

// ---------------------------------------------------------------------------
// Plain GEMM: C = act(A@Bt^T + bias). M%128==0, N%128==0.
// ---------------------------------------------------------------------------
template <int ACT>  // 0 none, 1 tanh
__global__ __launch_bounds__(256) void plain_gemm(
    const ushort_t* __restrict__ A, int lda, int K,
    const ushort_t* __restrict__ Bt,
    const float* __restrict__ bias, int bias_n,
    float* __restrict__ C, ushort_t* __restrict__ Cbf, int N)
{
    __shared__ __align__(16) ushort_t lds[3 * 8192];
    const int bm = blockIdx.x * 128, bn = blockIdx.y * 128;
    f4v acc[4][4] = {};
    gemm_core(A, nullptr, lda, K, Bt, nullptr, 0, 0, nullptr, bm, bn, lds, acc);

    const int tid = threadIdx.x, wid = tid >> 6, lane = tid & 63;
    const int wr = wid >> 1, wc = wid & 1, lrow = lane & 15, lkg = lane >> 4;
#pragma unroll
    for (int m = 0; m < 4; ++m) {
        const int row0 = bm + wr * 64 + m * 16 + lkg * 4;
#pragma unroll
        for (int n = 0; n < 4; ++n) {
            const int col = bn + wc * 64 + n * 16 + lrow;
            const float bv = (bias != nullptr && col < bias_n) ? bias[col] : 0.f;
#pragma unroll
            for (int r = 0; r < 4; ++r) {
                float v = acc[m][n][r] + bv;
                if (ACT == 1) v = tanh_f(v);
                const size_t o = (size_t)(row0 + r) * N + col;
                if (C != nullptr) C[o] = v;
                if (Cbf != nullptr) Cbf[o] = f2bf(v);
            }
        }
    }
}

// ---------------------------------------------------------------------------
// Fused LSTM step: two independent problems (L1 of step s+1 and L2 of step s),
// LSTM cell fused in epilogue. Weights gate-interleaved:
// col' = (j>>4)*64 + g*16 + (j&15).  1D grid, XCD-chunked swizzle.
// ---------------------------------------------------------------------------
struct Prob {
    const ushort_t* A1a; const ushort_t* A1b; int lda1; int K1;
    const ushort_t* B1t;
    const ushort_t* A2; int lda2; int K2; const ushort_t* B2t;
    const ushort_t* Dbf;   // bf16 [M][4096] pre-gates (incl. bias), or null
    const float* bias;     // fp32 [4096] permuted combined bias, or null
    float* cst;            // fp32 [M][1024] cell state (in/out)
    ushort_t* hout;        // bf16 [M][1024] new hidden
    ushort_t* hs;          // optional extra hidden dest
    int step_s;            // -1: identity; >=0: decoder hs mapping
};

__global__ __launch_bounds__(256) void lstm_step(Prob PA, int nxa, Prob PB,
                                                 int mshift)
{
    __shared__ __align__(16) ushort_t lds[3 * 8192];
    // XCD-chunked swizzle: each XCD gets a contiguous chunk (few N-panels).
    const int nblk = gridDim.x;
    const int wg = blockIdx.x;
    const int swz = (wg & 7) * (nblk >> 3) + (wg >> 3);
    const int nmb = 1 << mshift;
    const int nb = swz >> mshift;
    const int mb = swz & (nmb - 1);

    const bool isA = mb < nxa;
    const Prob& P = isA ? PA : PB;
    const int bm = (isA ? mb : mb - nxa) * 128;
    const int bn = nb * 128;

    f4v acc[4][4] = {};
    gemm_core(P.A1a, P.A1b, P.lda1, P.K1, P.B1t,
              P.A2, P.lda2, P.K2, P.B2t, bm, bn, lds, acc);

    const int tid = threadIdx.x, wid = tid >> 6, lane = tid & 63;
    const int wr = wid >> 1, wc = wid & 1, lrow = lane & 15, lkg = lane >> 4;
    const int colbase = bn + wc * 64;           // 64-aligned
    const int jb = (colbase >> 6) * 16 + lrow;  // hidden-unit index

#pragma unroll
    for (int m = 0; m < 4; ++m) {
        const int row0 = bm + wr * 64 + m * 16 + lkg * 4;
#pragma unroll
        for (int r = 0; r < 4; ++r) {
            const int row = row0 + r;
            float g0 = acc[m][0][r], g1 = acc[m][1][r];
            float g2 = acc[m][2][r], g3 = acc[m][3][r];
            if (P.Dbf != nullptr) {
                const ushort_t* d = P.Dbf + (size_t)row * 4096 + colbase + lrow;
                g0 += bf2f(d[0]); g1 += bf2f(d[16]);
                g2 += bf2f(d[32]); g3 += bf2f(d[48]);
            }
            if (P.bias != nullptr) {
                const float* b = P.bias + colbase + lrow;
                g0 += b[0]; g1 += b[16]; g2 += b[32]; g3 += b[48];
            }
            const size_t ci = (size_t)row * 1024 + jb;
            const float cn = fmaf(sigm_f(g1), P.cst[ci], sigm_f(g0) * tanh_f(g2));
            const float hn = sigm_f(g3) * tanh_f(cn);
            P.cst[ci] = cn;
            const ushort_t hb = f2bf(hn);
            P.hout[ci] = hb;
            if (P.hs != nullptr) {
                size_t d;
                if (P.step_s >= 0) {
                    const int u = row >> 9, b = row & 511;
                    d = ((size_t)((u * 16 + P.step_s) * 512 + b) << 10) + jb;
                } else {
                    d = ci;
                }
                P.hs[d] = hb;
            }
        }
    }
}

// ---------------------------------------------------------------------------
// Setup kernels
// ---------------------------------------------------------------------------
template <int PERM>
__global__ __launch_bounds__(256) void transpose_to_bf16(
    const float* __restrict__ in, ushort_t* __restrict__ out,
    int K, int N, int Kp, int Np)
{
    __shared__ float tile[32][33];
    const int k0 = blockIdx.x * 32, n0 = blockIdx.y * 32;
    const int tx = threadIdx.x, ty = threadIdx.y;  // 32 x 8
#pragma unroll
    for (int q = 0; q < 4; ++q) {
        const int k = k0 + ty + 8 * q, n = n0 + tx;
        tile[ty + 8 * q][tx] = (k < K && n < N) ? in[(size_t)k * N + n] : 0.f;
    }
    __syncthreads();
#pragma unroll
    for (int q = 0; q < 4; ++q) {
        const int n = n0 + ty + 8 * q, k = k0 + tx;
        int np = n;
        if (PERM) np = ((n & 1023) >> 4) * 64 + (n >> 10) * 16 + (n & 15);
        out[(size_t)np * Kp + k] = f2bf(tile[tx][ty + 8 * q]);
    }
}

__global__ void convert_pad_bf16(const float* __restrict__ in,
                                 ushort_t* __restrict__ out,
                                 int K, int Kp, int total)
{
    const int idx = blockIdx.x * 256 + threadIdx.x;
    if (idx >= total) return;
    const int r = idx / Kp, k = idx - r * Kp;
    out[idx] = (k < K) ? f2bf(in[(size_t)r * K + k]) : (ushort_t)0;
}

__global__ void sos_init_bf16(ushort_t* __restrict__ sos)
{
    const int i = blockIdx.x * 256 + threadIdx.x;
    if (i < 512 * 288) sos[i] = ((i % 288) == 0) ? (ushort_t)0x3F80 : (ushort_t)0;
}

__global__ void permute_bias(const float* __restrict__ b1,
                             const float* __restrict__ b2,
                             float* __restrict__ out)
{
    const int c = blockIdx.x * 256 + threadIdx.x;
    if (c >= 4096) return;
    const int g = (c >> 4) & 3;
    const int j = (c >> 6) * 16 + (c & 15);
    out[c] = b1[g * 1024 + j] + b2[g * 1024 + j];
}

// One block per row of logits [16384][384] (valid cols 0..257); row = t*512+b.
__global__ __launch_bounds__(256) void logsoftmax_kernel(
    const float* __restrict__ logits, float* __restrict__ out)
{
    const int row = blockIdx.x;
    const int tid = threadIdx.x;
    const float* L = logits + (size_t)row * 384;
    const int t = row >> 9;
    const int b = row & 511;
    float* O = out + ((size_t)b * 32 + t) * 258;

    const float x0 = L[tid];
    const float x1 = (tid < 2) ? L[256 + tid] : -1e30f;

    __shared__ float sm[4];
    float m = fmaxf(x0, x1);
#pragma unroll
    for (int off = 32; off > 0; off >>= 1) m = fmaxf(m, __shfl_down(m, off));
    if ((tid & 63) == 0) sm[tid >> 6] = m;
    __syncthreads();
    m = fmaxf(fmaxf(sm[0], sm[1]), fmaxf(sm[2], sm[3]));
    __syncthreads();

    float s = expf(x0 - m) + ((tid < 2) ? expf(x1 - m) : 0.f);
#pragma unroll
    for (int off = 32; off > 0; off >>= 1) s += __shfl_down(s, off);
    if ((tid & 63) == 0) sm[tid >> 6] = s;
    __syncthreads();
    s = sm[0] + sm[1] + sm[2] + sm[3];

    const float lse = m + logf(s);
    O[tid] = x0 - lse;
    if (tid < 2) O[256 + tid] = x1 - lse;
}

}  // namespace

extern "C" void kernel_launch(void* const* d_in, const int* in_sizes, int n_in,
                              void* d_out, int out_size, void* d_ws, size_t ws_size,
                              hipStream_t stream)
{
    (void)in_sizes; (void)n_in; (void)out_size; (void)ws_size;

    const float* z    = (const float*)d_in[0];
    const float* x    = (const float*)d_in[1];
    const float* cin  = (const float*)d_in[2];
    const float* ciW  = (const float*)d_in[3];
    const float* cib  = (const float*)d_in[4];
    const float* cW1i = (const float*)d_in[5];
    const float* cW1h = (const float*)d_in[6];
    const float* cb1i = (const float*)d_in[7];
    const float* cb1h = (const float*)d_in[8];
    const float* cW2i = (const float*)d_in[9];
    const float* cW2h = (const float*)d_in[10];
    const float* cb2i = (const float*)d_in[11];
    const float* cb2h = (const float*)d_in[12];
    const float* coW  = (const float*)d_in[13];
    const float* cob  = (const float*)d_in[14];
    const float* diW  = (const float*)d_in[15];
    const float* dib  = (const float*)d_in[16];
    const float* dW1i = (const float*)d_in[17];
    const float* dW1h = (const float*)d_in[18];
    const float* db1i = (const float*)d_in[19];
    const float* db1h = (const float*)d_in[20];
    const float* dW2i = (const float*)d_in[21];
    const float* dW2h = (const float*)d_in[22];
    const float* db2i = (const float*)d_in[23];
    const float* db2h = (const float*)d_in[24];
    const float* fcW  = (const float*)d_in[25];
    const float* fcb  = (const float*)d_in[26];
    float* out = (float*)d_out;

    // ---- workspace ----
    char* wsp = (char*)d_ws;
    size_t off = 0;
    auto allocf = [&](size_t n) { float* p = (float*)(wsp + off); off += n * 4; return p; };
    auto allocb = [&](size_t n) { ushort_t* p = (ushort_t*)(wsp + off); off += n * 2; return p; };

    float* cst = allocf((size_t)3 * 1024 * 1024 + 64);
    float* c1c = cst;
    float* c2c = cst + (size_t)512 * 1024;
    float* c1d = cst + (size_t)1024 * 1024;
    float* c2d = cst + (size_t)2 * 1024 * 1024;
    float* pb1c = allocf(4096);
    float* pb2c = allocf(4096);
    float* pb1d = allocf(4096);
    float* pb2d = allocf(4096);
    float* logits = allocf((size_t)16384 * 384);

    ushort_t* h2z  = allocb((size_t)2 * (512 + 1024) * 1024);
    ushort_t* hc2A = h2z;
    ushort_t* hc2B = h2z + (size_t)512 * 1024;
    ushort_t* h2dA = h2z + (size_t)2 * 512 * 1024;
    ushort_t* h2dB = h2z + (size_t)(2 * 512 + 1024) * 1024;

    ushort_t* hc1A = allocb((size_t)512 * 1024);
    ushort_t* hc1B = allocb((size_t)512 * 1024);
    ushort_t* h1dA = allocb((size_t)1024 * 1024);
    ushort_t* h1dB = allocb((size_t)1024 * 1024);

    ushort_t* zbf    = allocb((size_t)512 * 512);
    ushort_t* cinbf  = allocb((size_t)512 * 288);
    ushort_t* sosbf  = allocb((size_t)512 * 288);
    ushort_t* xbf    = allocb((size_t)16384 * 288);
    ushort_t* chbf   = allocb((size_t)1024 * 1024);
    ushort_t* ccode  = allocb((size_t)1024 * 512);
    ushort_t* cpre   = allocb((size_t)1024 * 4096);
    ushort_t* xW1c   = allocb((size_t)512 * 4096);
    ushort_t* hsbf   = allocb((size_t)16384 * 1024);

    ushort_t* ciWt  = allocb((size_t)1024 * 512);
    ushort_t* cW1it = allocb((size_t)4096 * 288);
    ushort_t* cW1ht = allocb((size_t)4096 * 1024);
    ushort_t* cW2it = allocb((size_t)4096 * 1024);
    ushort_t* cW2ht = allocb((size_t)4096 * 1024);
    ushort_t* coWt  = allocb((size_t)512 * 1024);
    ushort_t* dtopt = allocb((size_t)4096 * 512);
    ushort_t* dbott = allocb((size_t)4096 * 288);
    ushort_t* diWt  = allocb((size_t)1024 * 512);
    ushort_t* dW1ht = allocb((size_t)4096 * 1024);
    ushort_t* dW2it = allocb((size_t)4096 * 1024);
    ushort_t* dW2ht = allocb((size_t)4096 * 1024);
    ushort_t* fcWt  = allocb((size_t)384 * 1024);

    hipMemsetAsync(cst, 0, (size_t)3 * 1024 * 1024 * 4, stream);
    hipMemsetAsync(h2z, 0, (size_t)2 * (512 + 1024) * 1024 * 2, stream);

    // ---- weight prep ----
    auto transp = [&](const float* in, ushort_t* o, int K, int N, int Kp, int Np, int perm) {
        dim3 g(Kp / 32, Np / 32), b(32, 8);
        if (perm) transpose_to_bf16<1><<<g, b, 0, stream>>>(in, o, K, N, Kp, Np);
        else      transpose_to_bf16<0><<<g, b, 0, stream>>>(in, o, K, N, Kp, Np);
    };
    transp(ciW, ciWt, 512, 1024, 512, 1024, 0);
    transp(cW1i, cW1it, 258, 4096, 288, 4096, 1);
    transp(cW1h, cW1ht, 1024, 4096, 1024, 4096, 1);
    transp(cW2i, cW2it, 1024, 4096, 1024, 4096, 1);
    transp(cW2h, cW2ht, 1024, 4096, 1024, 4096, 1);
    transp(coW, coWt, 1024, 512, 1024, 512, 0);
    transp(dW1i, dtopt, 512, 4096, 512, 4096, 1);
    transp(dW1i + (size_t)512 * 4096, dbott, 258, 4096, 288, 4096, 1);
    transp(diW, diWt, 512, 1024, 512, 1024, 0);
    transp(dW1h, dW1ht, 1024, 4096, 1024, 4096, 1);
    transp(dW2i, dW2it, 1024, 4096, 1024, 4096, 1);
    transp(dW2h, dW2ht, 1024, 4096, 1024, 4096, 1);
    transp(fcW, fcWt, 1024, 258, 1024, 384, 0);

    auto convert = [&](const float* in, ushort_t* o, int K, int Kp, int R) {
        const int total = R * Kp;
        convert_pad_bf16<<<dim3((total + 255) / 256), 256, 0, stream>>>(in, o, K, Kp, total);
    };
    convert(z, zbf, 512, 512, 512);
    convert(cin, cinbf, 258, 288, 512);
    convert(x, xbf, 258, 288, 16384);
    sos_init_bf16<<<dim3((512 * 288 + 255) / 256), 256, 0, stream>>>(sosbf);
    permute_bias<<<16, 256, 0, stream>>>(cb1i, cb1h, pb1c);
    permute_bias<<<16, 256, 0, stream>>>(cb2i, cb2h, pb2c);
    permute_bias<<<16, 256, 0, stream>>>(db1i, db1h, pb1d);
    permute_bias<<<16, 256, 0, stream>>>(db2i, db2h, pb2d);

    auto gemm = [&](int act, const ushort_t* A, int lda, int K, const ushort_t* Bt,
                    const float* bias, int bias_n,
                    float* C, ushort_t* Cbf, int M, int N) {
        dim3 g(M / 128, N / 128);
        if (act) plain_gemm<1><<<g, 256, 0, stream>>>(A, lda, K, Bt, bias, bias_n, C, Cbf, N);
        else     plain_gemm<0><<<g, 256, 0, stream>>>(A, lda, K, Bt, bias, bias_n, C, Cbf, N);
    };

    // ---- conductor init ----
    gemm(1, zbf, 512, 512, ciWt, cib, 1024, nullptr, hc1A, 512, 1024);
    gemm(0, cinbf, 288, 288, cW1it, pb1c, 4096, nullptr, xW1c, 512, 4096);

    // ---- conductor: 3 fused iterations (L1 at k=0,1; L2 at k=1,2) ----
    ushort_t* HC1[2] = {hc1A, hc1B};
    ushort_t* HC2[2] = {hc2A, hc2B};
    for (int k = 0; k <= 2; ++k) {
        Prob pa{}, pb{};
        int nxa = 0, nxb = 0;
        if (k < 2) {
            pa = {HC1[k & 1], nullptr, 1024, 1024, cW1ht,
                  nullptr, 0, 0, nullptr,
                  xW1c, nullptr, c1c, HC1[(k + 1) & 1], nullptr, -1};
            nxa = 4;
        }
        if (k >= 1) {
            pb = {HC1[k & 1], nullptr, 1024, 1024, cW2it,
                  HC2[k & 1], 1024, 1024, cW2ht,
                  nullptr, pb2c, c2c, HC2[(k + 1) & 1],
                  chbf + (size_t)(k - 1) * 512 * 1024, -1};
            nxb = 4;
        }
        const int nmb = nxa + nxb;               // 4 or 8 (power of 2)
        const int mshift = (nmb == 4) ? 2 : 3;
        lstm_step<<<dim3(nmb * 32), 256, 0, stream>>>(pa, nxa, pb, mshift);
    }

    // ---- codes + decoder init ----
    gemm(0, chbf, 1024, 1024, coWt, cob, 512, nullptr, ccode, 1024, 512);
    gemm(0, ccode, 512, 512, dtopt, pb1d, 4096, nullptr, cpre, 1024, 4096);
    gemm(1, ccode, 512, 512, diWt, dib, 1024, nullptr, h1dA, 1024, 1024);

    // ---- decoder: 17 fused iterations (L1 at k=0..15; L2 at k=1..16) ----
    ushort_t* H1[2] = {h1dA, h1dB};
    ushort_t* H2[2] = {h2dA, h2dB};
    for (int k = 0; k <= 16; ++k) {
        Prob pa{}, pb{};
        int nxa = 0, nxb = 0;
        if (k < 16) {
            const ushort_t* plo = (k == 0) ? sosbf : (xbf + (size_t)(k - 1) * 512 * 288);
            const ushort_t* phi = xbf + (size_t)(15 + k) * 512 * 288;
            pa = {plo, phi, 288, 288, dbott,
                  H1[k & 1], 1024, 1024, dW1ht,
                  cpre, nullptr, c1d, H1[(k + 1) & 1], nullptr, -1};
            nxa = 8;
        }
        if (k >= 1) {
            pb = {H1[k & 1], nullptr, 1024, 1024, dW2it,
                  H2[k & 1], 1024, 1024, dW2ht,
                  nullptr, pb2d, c2d, H2[(k + 1) & 1], hsbf, k - 1};
            nxb = 8;
        }
        const int nmb = nxa + nxb;               // 8 or 16
        const int mshift = (nmb == 8) ? 3 : 4;
        lstm_step<<<dim3(nmb * 32), 256, 0, stream>>>(pa, nxa, pb, mshift);
    }

    // ---- projection + log_softmax ----
    gemm(0, hsbf, 1024, 1024, fcWt, fcb, 258, logits, nullptr, 16384, 384);
    logsoftmax_kernel<<<dim3(16384), 256, 0, stream>>>(logits, out);
}